// Round 10
// baseline (120.510 us; speedup 1.0000x reference)
//
#include <hip/hip_runtime.h>
#include <hip/hip_bf16.h>

#define NB 4096
#define DD 768
#define NKT 24            // K-tiles of BK=32: 768/32
#define NBLK 512          // grid: 512 blocks = 2 per CU (77KB LDS, <=128 VGPR) -> all co-resident

typedef __bf16 bf16x8 __attribute__((ext_vector_type(8)));
typedef float f32x4 __attribute__((ext_vector_type(4)));
typedef unsigned int uint;

#define WAITVM(N) asm volatile("s_waitcnt vmcnt(" #N ")" ::: "memory")
#define WAITLGKM0 asm volatile("s_waitcnt lgkmcnt(0)" ::: "memory")

// ---------------- init: zero stats + grid-barrier counter (d_ws is poisoned 0xAA) ----------------
__global__ void init_kernel(float* scal)
{
    if (threadIdx.x < 16) scal[threadIdx.x] = 0.0f;
}

// ---------------- staging: one K-tile unit = A[256][32] + B[128][32] (24 KB), ring of 3 ----------------
// Unit layout: 1536 chunks of 16B; chunk c<1024 = A (row=c>>2, physchunk=c&3), c>=1024 = B.
// Swizzle both-sides (rule #21): logical k-chunk lc of row r stored at phys chunk lc^((r>>1)&3);
// staging loads global chunk lc = pc ^ ((row>>1)&3) into linear phys slot pc.
// A-phase: 2 loads/thread (chunks t, t+512); B-phase: 1 load/thread (chunk t+1024).
__device__ __forceinline__ void stage_A(
    __hip_bfloat16* ldsAll, const __hip_bfloat16* __restrict__ vhat,
    int rowBase, int T, int wid, int lane)
{
    int k0 = T * 32;
    __hip_bfloat16* ub = ldsAll + (T % 3) * 12288;
    #pragma unroll
    for (int i = 0; i < 2; ++i) {
        int cw = wid * 64 + i * 512;          // wave-uniform chunk base
        int c  = cw + lane;
        int row = c >> 2, pc = c & 3;
        int lc = pc ^ ((row >> 1) & 3);
        const __hip_bfloat16* g = vhat + (size_t)(rowBase + row) * DD + k0 + lc * 8;
        __builtin_amdgcn_global_load_lds(
            (const __attribute__((address_space(1))) void*)g,
            (__attribute__((address_space(3))) void*)(ub + cw * 8),
            16, 0, 0);
    }
}
__device__ __forceinline__ void stage_B(
    __hip_bfloat16* ldsAll, const __hip_bfloat16* __restrict__ that_,
    int colBase, int T, int wid, int lane)
{
    int k0 = T * 32;
    __hip_bfloat16* ub = ldsAll + (T % 3) * 12288;
    int cw = wid * 64;
    int c  = cw + lane;                        // [0,512) within B region
    int row = c >> 2, pc = c & 3;
    int lc = pc ^ ((row >> 1) & 3);
    const __hip_bfloat16* g = that_ + (size_t)(colBase + row) * DD + k0 + lc * 8;
    __builtin_amdgcn_global_load_lds(
        (const __attribute__((address_space(1))) void*)g,
        (__attribute__((address_space(3))) void*)(ub + 8192 + cw * 8),
        16, 0, 0);
}

// ---------------- fully fused: normalize+cnt | bar1 | GEMM+stats | bar2 | exp sums | bar3 | loss ----------------
__global__ __launch_bounds__(512, 4) void fused_kernel(
    const float* __restrict__ vf, const float* __restrict__ tf, const int* __restrict__ ids,
    __hip_bfloat16* __restrict__ vhat, __hip_bfloat16* __restrict__ that_,
    float* scal, float* rs, float* cs, float* cntf, int* npart, uint* bar,
    float* __restrict__ out)
{
    __shared__ __hip_bfloat16 ldsAll[3 * 12288];   // 72 KB ring; reused as ids stage in phase 0
    __shared__ int idr[256], idc[128];
    __shared__ float red[24];
    __shared__ float rs_l[256], cs_l[128];
    __shared__ int bp[8], wred_i[8];
    __shared__ float ra[8], rn[8];
    __shared__ float invT_sh, mf_sh;

    int rawb = blockIdx.x;
    int t = threadIdx.x, wid = t >> 6, lane = t & 63;

    // ===== phase 0a: normalize 16 rows (1 wave = 1 row, nontemporal f32x4 loads) =====
    #pragma unroll
    for (int it = 0; it < 2; ++it) {
        int row = rawb * 16 + wid * 2 + it;
        const float* src;
        __hip_bfloat16* dst;
        if (row < NB) { src = vf + (size_t)row * DD; dst = vhat + (size_t)row * DD; }
        else          { src = tf + (size_t)(row - NB) * DD; dst = that_ + (size_t)(row - NB) * DD; }
        f32x4 x0 = __builtin_nontemporal_load((const f32x4*)(src + lane * 4));
        f32x4 x1 = __builtin_nontemporal_load((const f32x4*)(src + 256 + lane * 4));
        f32x4 x2 = __builtin_nontemporal_load((const f32x4*)(src + 512 + lane * 4));
        float s = x0[0]*x0[0] + x0[1]*x0[1] + x0[2]*x0[2] + x0[3]*x0[3]
                + x1[0]*x1[0] + x1[1]*x1[1] + x1[2]*x1[2] + x1[3]*x1[3]
                + x2[0]*x2[0] + x2[1]*x2[1] + x2[2]*x2[2] + x2[3]*x2[3];
        #pragma unroll
        for (int off = 1; off < 64; off <<= 1) s += __shfl_xor(s, off, 64);
        float scale = 1.0f / sqrtf(s);
        unsigned short* dsh = (unsigned short*)dst;
        ushort4 o0, o1, o2;
        o0.x = __builtin_bit_cast(unsigned short, __float2bfloat16(x0[0] * scale));
        o0.y = __builtin_bit_cast(unsigned short, __float2bfloat16(x0[1] * scale));
        o0.z = __builtin_bit_cast(unsigned short, __float2bfloat16(x0[2] * scale));
        o0.w = __builtin_bit_cast(unsigned short, __float2bfloat16(x0[3] * scale));
        o1.x = __builtin_bit_cast(unsigned short, __float2bfloat16(x1[0] * scale));
        o1.y = __builtin_bit_cast(unsigned short, __float2bfloat16(x1[1] * scale));
        o1.z = __builtin_bit_cast(unsigned short, __float2bfloat16(x1[2] * scale));
        o1.w = __builtin_bit_cast(unsigned short, __float2bfloat16(x1[3] * scale));
        o2.x = __builtin_bit_cast(unsigned short, __float2bfloat16(x2[0] * scale));
        o2.y = __builtin_bit_cast(unsigned short, __float2bfloat16(x2[1] * scale));
        o2.z = __builtin_bit_cast(unsigned short, __float2bfloat16(x2[2] * scale));
        o2.w = __builtin_bit_cast(unsigned short, __float2bfloat16(x2[3] * scale));
        *(ushort4*)(dsh + lane * 4)       = o0;
        *(ushort4*)(dsh + 256 + lane * 4) = o1;
        *(ushort4*)(dsh + 512 + lane * 4) = o2;
    }

    // ===== phase 0b: cnt — ids staged into ldsAll; 1 wave per id, int4 scan =====
    int* idsh = (int*)ldsAll;
    for (int i = t; i < NB; i += 512) idsh[i] = ids[i];
    __syncthreads();
    {
        int my = idsh[rawb * 8 + wid];
        const int4* idsh4 = (const int4*)idsh;
        int c = 0;
        #pragma unroll 4
        for (int j = lane; j < NB / 4; j += 64) {
            int4 v = idsh4[j];
            c += (v.x == my) + (v.y == my) + (v.z == my) + (v.w == my);
        }
        #pragma unroll
        for (int off = 32; off > 0; off >>= 1) c += __shfl_down(c, off, 64);
        if (lane == 0) { cntf[rawb * 8 + wid] = (float)c; bp[wid] = c; }
    }
    // ===== phase 0c: zero rs+cs (contiguous 8192 floats starting at rs) =====
    if (t < 16) rs[rawb * 16 + t] = 0.0f;
    __syncthreads();
    if (t == 0) {
        int s = 0;
        #pragma unroll
        for (int i = 0; i < 8; ++i) s += bp[i];
        npart[rawb] = s;
    }

    // ===== grid barrier #1: vhat/that/cntf/npart/rs-zero published =====
    __syncthreads();
    if (t == 0) {
        __hip_atomic_fetch_add(bar, 1u, __ATOMIC_ACQ_REL, __HIP_MEMORY_SCOPE_AGENT);
        while (__hip_atomic_load(bar, __ATOMIC_ACQUIRE, __HIP_MEMORY_SCOPE_AGENT) < NBLK)
            __builtin_amdgcn_s_sleep(2);
    }
    __syncthreads();

    // ===== GEMM: 256x128 tile, 8 waves (4M x 2N), BK=32, ring-3, R8 2-phase schedule =====
    // XCD-chunked bijective swizzle: 8 regions of 4by x 16bx (grid 512 = 16 x 32)
    int rg = rawb & 7, sq = rawb >> 3;                 // sq in [0,64)
    int by = (rg >> 1) * 4 + (sq >> 4);                // [0,16)
    int bx = (rg & 1) * 16 + (sq & 15);                // [0,32)
    int rowBase = by * 256, colBase = bx * 128;
    int wr = wid >> 1, wc = wid & 1;                   // wave = 64-row x 64-col output block
    int fr = lane & 15, g = lane >> 4;

    f32x4 acc[4][4];
    #pragma unroll
    for (int m = 0; m < 4; ++m)
        #pragma unroll
        for (int n = 0; n < 4; ++n) acc[m][n] = (f32x4){0.f, 0.f, 0.f, 0.f};

    int pcoff = ((g ^ ((fr >> 1) & 3)) * 8);
    int aoff = (wr * 64 + fr) * 32 + pcoff;            // A rows: wr*64 + m*16 + fr
    int boff = 8192 + (wc * 64 + fr) * 32 + pcoff;     // B rows: wc*64 + n*16 + fr

    // prologue: stage tiles 0,1 (6 loads/thread); tile0 complete -> vmcnt(3)
    stage_A(ldsAll, vhat, rowBase, 0, wid, lane);
    stage_B(ldsAll, that_, colBase, 0, wid, lane);
    stage_A(ldsAll, vhat, rowBase, 1, wid, lane);
    stage_B(ldsAll, that_, colBase, 1, wid, lane);
    WAITVM(3);
    __builtin_amdgcn_s_barrier();

    // Ledger: start of tile T -> 3 outstanding (T+1's). During T issue 3 (T+2).
    // Boundary vmcnt(3) retires T+1's. Unit (T+2)%3 == (T-1)%3: T-1's reads retired
    // before T-1's end barrier (lgkmcnt(0) precedes its MFMAs).
    for (int T = 0; T < NKT; ++T) {
        const __hip_bfloat16* U = ldsAll + (T % 3) * 12288;
        // phase A: reads a[0..1], b[0..3] || stage_A(T+2) -> BAR -> 8 MFMA
        bf16x8 a0[2], bb[4];
        #pragma unroll
        for (int m = 0; m < 2; ++m) a0[m] = *(const bf16x8*)(U + aoff + m * 512);
        #pragma unroll
        for (int n = 0; n < 4; ++n) bb[n] = *(const bf16x8*)(U + boff + n * 512);
        if (T + 2 < NKT) stage_A(ldsAll, vhat, rowBase, T + 2, wid, lane);
        __builtin_amdgcn_sched_barrier(0);
        __builtin_amdgcn_s_barrier();
        WAITLGKM0;
        __builtin_amdgcn_sched_barrier(0);
        __builtin_amdgcn_s_setprio(1);
        #pragma unroll
        for (int m = 0; m < 2; ++m)
            #pragma unroll
            for (int n = 0; n < 4; ++n)
                acc[m][n] = __builtin_amdgcn_mfma_f32_16x16x32_bf16(a0[m], bb[n], acc[m][n], 0, 0, 0);
        __builtin_amdgcn_s_setprio(0);
        __builtin_amdgcn_sched_barrier(0);
        __builtin_amdgcn_s_barrier();
        // phase B: reads a[2..3] || stage_B(T+2) -> BAR -> 8 MFMA
        bf16x8 a1[2];
        #pragma unroll
        for (int m = 0; m < 2; ++m) a1[m] = *(const bf16x8*)(U + aoff + (m + 2) * 512);
        if (T + 2 < NKT) stage_B(ldsAll, that_, colBase, T + 2, wid, lane);
        __builtin_amdgcn_sched_barrier(0);
        __builtin_amdgcn_s_barrier();
        WAITLGKM0;
        __builtin_amdgcn_sched_barrier(0);
        __builtin_amdgcn_s_setprio(1);
        #pragma unroll
        for (int m = 0; m < 2; ++m)
            #pragma unroll
            for (int n = 0; n < 4; ++n)
                acc[m + 2][n] = __builtin_amdgcn_mfma_f32_16x16x32_bf16(a1[m], bb[n], acc[m + 2][n], 0, 0, 0);
        __builtin_amdgcn_s_setprio(0);
        __builtin_amdgcn_sched_barrier(0);
        // tile boundary: T+1 staged; keep T+2 in flight (never vmcnt 0 mid-loop)
        if (T < NKT - 2)       { WAITVM(3); }
        else if (T == NKT - 2) { WAITVM(0); }
        __builtin_amdgcn_s_barrier();
    }

    // ===== stats: {total, S_mf, trace};  C/D: col=fr, row=g*4+reg [m89-verified] =====
    if (t < 256) idr[t] = ids[rowBase + t];
    else if (t < 384) idc[t - 256] = ids[colBase + (t - 256)];
    __syncthreads();
    {
        float tsum = 0.f, msum = 0.f, dsum = 0.f;
        #pragma unroll
        for (int m = 0; m < 4; ++m) {
            int rl = wr * 64 + m * 16 + g * 4;
            #pragma unroll
            for (int n = 0; n < 4; ++n) {
                int cl = wc * 64 + n * 16 + fr;
                int colId = idc[cl];
                int gj = colBase + cl;
                #pragma unroll
                for (int r = 0; r < 4; ++r) {
                    float val = acc[m][n][r];
                    tsum += val;
                    if (idr[rl + r] == colId) msum += val;
                    if (rowBase + rl + r == gj) dsum += val;
                }
            }
        }
        #pragma unroll
        for (int off = 32; off > 0; off >>= 1) {
            tsum += __shfl_down(tsum, off, 64);
            msum += __shfl_down(msum, off, 64);
            dsum += __shfl_down(dsum, off, 64);
        }
        if (lane == 0) { red[wid] = tsum; red[8 + wid] = msum; red[16 + wid] = dsum; }
        __syncthreads();
        if (t == 0) {
            float s0 = 0.f, s1 = 0.f, s2 = 0.f;
            #pragma unroll
            for (int w = 0; w < 8; ++w) { s0 += red[w]; s1 += red[8 + w]; s2 += red[16 + w]; }
            atomicAdd(&scal[0], s0);
            atomicAdd(&scal[1], s1);
            atomicAdd(&scal[2], s2);
        }
    }

    // ===== grid barrier #2: stats complete =====
    __syncthreads();
    if (t == 0) {
        __hip_atomic_fetch_add(bar, 1u, __ATOMIC_ACQ_REL, __HIP_MEMORY_SCOPE_AGENT);
        while (__hip_atomic_load(bar, __ATOMIC_ACQUIRE, __HIP_MEMORY_SCOPE_AGENT) < 2 * NBLK)
            __builtin_amdgcn_s_sleep(2);
    }
    __syncthreads();

    // ===== np reduce + invT (per block) =====
    {
        int myn = npart[t & (NBLK - 1)];
        #pragma unroll
        for (int off = 32; off > 0; off >>= 1) myn += __shfl_down(myn, off, 64);
        if (lane == 0) wred_i[wid] = myn;
        __syncthreads();
        if (t == 0) {
            int npi = 0;
            #pragma unroll
            for (int w = 0; w < 8; ++w) npi += wred_i[w];
            float total = __hip_atomic_load(&scal[0], __ATOMIC_RELAXED, __HIP_MEMORY_SCOPE_AGENT);
            float mf    = __hip_atomic_load(&scal[1], __ATOMIC_RELAXED, __HIP_MEMORY_SCOPE_AGENT);
            float trace = __hip_atomic_load(&scal[2], __ATOMIC_RELAXED, __HIP_MEMORY_SCOPE_AGENT);
            float np = (float)npi;
            float pos_cnt = np - (float)NB;
            float neg_cnt = (float)NB * (float)NB - np;
            float pos_mean = (mf - trace) / fmaxf(1.0f, pos_cnt);
            float neg_mean = (total - mf) / fmaxf(1.0f, neg_cnt);
            float sep = pos_mean - neg_mean;
            float temp = 0.07f * (0.8f + 0.4f * expf(-2.0f * sep));
            temp = fminf(fmaxf(temp, 0.04f), 0.2f);
            invT_sh = 1.0f / temp;
            mf_sh = mf;
        }
        if (t < 256) rs_l[t] = 0.0f;
        else if (t < 384) cs_l[t - 256] = 0.0f;
        __syncthreads();
    }
    float invT = invT_sh;

    // ===== exp((sim-1)/temp) row & col sums straight from registers =====
    #pragma unroll
    for (int m = 0; m < 4; ++m)
        #pragma unroll
        for (int n = 0; n < 4; ++n)
            #pragma unroll
            for (int r = 0; r < 4; ++r)
                acc[m][n][r] = __expf((acc[m][n][r] - 1.0f) * invT);
    #pragma unroll
    for (int m = 0; m < 4; ++m) {
        #pragma unroll
        for (int r = 0; r < 4; ++r) {
            float rp = 0.f;
            #pragma unroll
            for (int n = 0; n < 4; ++n) rp += acc[m][n][r];
            rp += __shfl_xor(rp, 1, 64);
            rp += __shfl_xor(rp, 2, 64);
            rp += __shfl_xor(rp, 4, 64);
            rp += __shfl_xor(rp, 8, 64);
            if (fr == 0) atomicAdd(&rs_l[wr * 64 + m * 16 + g * 4 + r], rp);
        }
    }
    #pragma unroll
    for (int n = 0; n < 4; ++n) {
        float cp = 0.f;
        #pragma unroll
        for (int m = 0; m < 4; ++m)
            #pragma unroll
            for (int r = 0; r < 4; ++r) cp += acc[m][n][r];
        cp += __shfl_xor(cp, 16, 64);
        cp += __shfl_xor(cp, 32, 64);
        if (g == 0) atomicAdd(&cs_l[wc * 64 + n * 16 + fr], cp);
    }
    __syncthreads();
    if (t < 256) atomicAdd(&rs[rowBase + t], rs_l[t]);
    else if (t < 384) atomicAdd(&cs[colBase + t - 256], cs_l[t - 256]);

    // ===== barrier #3: all arrive; only block 0 spins and finishes =====
    __syncthreads();
    if (t == 0)
        __hip_atomic_fetch_add(bar, 1u, __ATOMIC_ACQ_REL, __HIP_MEMORY_SCOPE_AGENT);
    if (rawb != 0) return;
    if (t == 0) {
        while (__hip_atomic_load(bar, __ATOMIC_ACQUIRE, __HIP_MEMORY_SCOPE_AGENT) < 3 * NBLK)
            __builtin_amdgcn_s_sleep(2);
    }
    __syncthreads();

    // ===== final loss (block 0, 512 threads) =====
    {
        float a = 0.f, npl = 0.f;
        for (int i = t; i < NB; i += 512) {
            float cf = cntf[i];
            a += cf * (logf(rs[i]) + logf(cs[i]));
            npl += cf;
        }
        #pragma unroll
        for (int off = 32; off > 0; off >>= 1) {
            a += __shfl_down(a, off, 64);
            npl += __shfl_down(npl, off, 64);
        }
        if (lane == 0) { ra[wid] = a; rn[wid] = npl; }
        __syncthreads();
        if (t == 0) {
            float A = 0.f, np = 0.f;
            #pragma unroll
            for (int w = 0; w < 8; ++w) { A += ra[w]; np += rn[w]; }
            // lse_row[i] = 1/temp + log(rs[i]); v2t+t2v = sum cnt*(lse_r+lse_c) - 2*mf/temp
            out[0] = (A + 2.0f * invT_sh * (np - mf_sh)) / (2.0f * np);
        }
    }
}

extern "C" void kernel_launch(void* const* d_in, const int* in_sizes, int n_in,
                              void* d_out, int out_size, void* d_ws, size_t ws_size,
                              hipStream_t stream)
{
    const float* vf  = (const float*)d_in[0];
    const float* tf  = (const float*)d_in[1];
    const int*   ids = (const int*)d_in[2];

    float* ws_f = (float*)d_ws;
    float* scal = ws_f;                 // [0]=total [1]=S_mf [2]=trace [6]=bar
    float* rs   = ws_f + 16;            // 4096  (cs contiguous after rs — fused zeroes both via rs)
    float* cs   = ws_f + 16 + 4096;     // 4096
    float* cntf = ws_f + 16 + 8192;     // 4096
    int* npart  = (int*)(ws_f + 16 + 12288);   // 512 partial num_pos counts
    uint* bar   = (uint*)(scal + 6);
    __hip_bfloat16* vhat  = (__hip_bfloat16*)((char*)d_ws + 131072);
    __hip_bfloat16* that_ = vhat + (size_t)NB * DD;

    init_kernel<<<1, 64, 0, stream>>>(scal);
    fused_kernel<<<NBLK, 512, 0, stream>>>(vf, tf, ids, vhat, that_,
                                           scal, rs, cs, cntf, npart, bar, (float*)d_out);
}

// Round 11
// 91.182 us; speedup vs baseline: 1.3216x; 1.3216x over previous
//
#include <hip/hip_runtime.h>
#include <hip/hip_bf16.h>

#define NB 4096
#define DD 768
#define NKT 24            // K-tiles of BK=32: 768/32
#define NBLK 256          // grid: 256 blocks = 1 per CU (128KB LDS forces 1/CU) -> all co-resident

typedef __bf16 bf16x8 __attribute__((ext_vector_type(8)));
typedef float f32x4 __attribute__((ext_vector_type(4)));
typedef unsigned int uint;

#define WAITVM(N) asm volatile("s_waitcnt vmcnt(" #N ")" ::: "memory")
#define WAITLGKM0 asm volatile("s_waitcnt lgkmcnt(0)" ::: "memory")

// ---------------- init: zero stats + grid-barrier counter (d_ws is poisoned 0xAA) ----------------
__global__ void init_kernel(float* scal)
{
    if (threadIdx.x < 16) scal[threadIdx.x] = 0.0f;
}

// ---------------- staging: one K-tile unit = A[256][32] + B[256][32] (32 KB) ----------------
// Swizzle (both sides, rule #21): logical chunk c (16B) of row r at phys chunk c ^ ((r>>1)&3).
// global_load_lds dest is linear (base+lane*16); lane's global source chunk = (lane&3)^((lane>>3)&3).
// Measured 0 bank conflicts (2-way aliasing = free, m136).
__device__ __forceinline__ void stage_range(
    __hip_bfloat16* ldsAll,
    const __hip_bfloat16* __restrict__ vhat, const __hip_bfloat16* __restrict__ that_,
    int rowBase, int colBase, int T, int i0, int i1, int wid, int lane)
{
    int u = T & 3;
    int k0 = T * 32;
    const __hip_bfloat16* src = (wid >= 4) ? that_ : vhat;
    int tb = (wid >= 4) ? colBase : rowBase;
    int w4 = wid & 3;
    int logc = (lane & 3) ^ ((lane >> 3) & 3);
    int rowIn = w4 * 64 + (lane >> 2);
    __hip_bfloat16* dbase = ldsAll + u * 16384 + ((wid >= 4) ? 8192 : 0) + w4 * 2048;
    #pragma unroll
    for (int i = i0; i <= i1; ++i) {
        const __hip_bfloat16* g = src + (size_t)(tb + rowIn + i * 16) * DD + k0 + logc * 8;
        __builtin_amdgcn_global_load_lds(
            (const __attribute__((address_space(1))) void*)g,
            (__attribute__((address_space(3))) void*)(dbase + i * 512),
            16, 0, 0);
    }
}

// ---------------- fully fused: normalize+cnt | bar1 | GEMM+stats | bar2 | exp sums | bar3 | loss ----------------
__global__ __launch_bounds__(512, 2) void fused_kernel(
    const float* __restrict__ vf, const float* __restrict__ tf, const int* __restrict__ ids,
    __hip_bfloat16* __restrict__ vhat, __hip_bfloat16* __restrict__ that_,
    float* scal, float* rs, float* cs, float* cntf, int* npart, uint* bar,
    float* __restrict__ out)
{
    __shared__ __hip_bfloat16 ldsAll[4 * 16384];   // 128 KB: ring units; reused as ids stage in phase 0
    __shared__ int idr[256], idc[256];
    __shared__ float red[24];
    __shared__ float rs_l[256], cs_l[256];
    __shared__ int bp[16], wred_i[8];
    __shared__ float ra[8], rn[8];
    __shared__ float invT_sh, mf_sh;

    int rawb = blockIdx.x;
    int t = threadIdx.x, wid = t >> 6, lane = t & 63;

    // ===== phase 0a: normalize 32 rows/block, 4 rows/wave with ALL loads issued up-front =====
    // (one HBM latency round instead of 4 serial rounds; ids loads ride along)
    {
        f32x4 xr[4][3];
        __hip_bfloat16* dsts[4];
        #pragma unroll
        for (int it = 0; it < 4; ++it) {
            int row = rawb * 32 + wid * 4 + it;
            const float* src;
            if (row < NB) { src = vf + (size_t)row * DD; dsts[it] = vhat + (size_t)row * DD; }
            else          { src = tf + (size_t)(row - NB) * DD; dsts[it] = that_ + (size_t)(row - NB) * DD; }
            xr[it][0] = __builtin_nontemporal_load((const f32x4*)(src + lane * 4));
            xr[it][1] = __builtin_nontemporal_load((const f32x4*)(src + 256 + lane * 4));
            xr[it][2] = __builtin_nontemporal_load((const f32x4*)(src + 512 + lane * 4));
        }
        int idreg[8];
        #pragma unroll
        for (int i = 0; i < 8; ++i) idreg[i] = ids[t + i * 512];

        #pragma unroll
        for (int it = 0; it < 4; ++it) {
            float s = 0.f;
            #pragma unroll
            for (int c = 0; c < 3; ++c)
                s += xr[it][c][0]*xr[it][c][0] + xr[it][c][1]*xr[it][c][1]
                   + xr[it][c][2]*xr[it][c][2] + xr[it][c][3]*xr[it][c][3];
            #pragma unroll
            for (int off = 1; off < 64; off <<= 1) s += __shfl_xor(s, off, 64);
            float scale = 1.0f / sqrtf(s);
            unsigned short* dsh = (unsigned short*)dsts[it];
            #pragma unroll
            for (int c = 0; c < 3; ++c) {
                ushort4 o;
                o.x = __builtin_bit_cast(unsigned short, __float2bfloat16(xr[it][c][0] * scale));
                o.y = __builtin_bit_cast(unsigned short, __float2bfloat16(xr[it][c][1] * scale));
                o.z = __builtin_bit_cast(unsigned short, __float2bfloat16(xr[it][c][2] * scale));
                o.w = __builtin_bit_cast(unsigned short, __float2bfloat16(xr[it][c][3] * scale));
                *(ushort4*)(dsh + c * 256 + lane * 4) = o;
            }
        }
        // ids -> LDS (loaded above, in flight during normalize math)
        int* idsh = (int*)ldsAll;
        #pragma unroll
        for (int i = 0; i < 8; ++i) idsh[t + i * 512] = idreg[i];
    }
    __syncthreads();

    // ===== phase 0b: cnt — 32 lanes per id, int4 LDS scan =====
    {
        int* idsh = (int*)ldsAll;
        int sub = t >> 5, l32 = t & 31;
        int my = idsh[rawb * 16 + sub];
        const int4* idsh4 = (const int4*)idsh;
        int c = 0;
        #pragma unroll 8
        for (int j = l32; j < NB / 4; j += 32) {
            int4 v = idsh4[j];
            c += (v.x == my) + (v.y == my) + (v.z == my) + (v.w == my);
        }
        #pragma unroll
        for (int off = 16; off > 0; off >>= 1) c += __shfl_down(c, off, 32);
        if (l32 == 0) { cntf[rawb * 16 + sub] = (float)c; bp[sub] = c; }
    }
    // ===== phase 0c: zero rs+cs (contiguous 8192 floats starting at rs) =====
    if (t < 32) rs[rawb * 32 + t] = 0.0f;
    __syncthreads();
    if (t == 0) {
        int s = 0;
        #pragma unroll
        for (int i = 0; i < 16; ++i) s += bp[i];
        npart[rawb] = s;
    }

    // ===== grid barrier #1: vhat/that/cntf/npart/rs-zero published =====
    __syncthreads();
    if (t == 0) {
        __hip_atomic_fetch_add(bar, 1u, __ATOMIC_ACQ_REL, __HIP_MEMORY_SCOPE_AGENT);
        while (__hip_atomic_load(bar, __ATOMIC_ACQUIRE, __HIP_MEMORY_SCOPE_AGENT) < NBLK)
            __builtin_amdgcn_s_sleep(2);
    }
    __syncthreads();

    // ===== GEMM: 256x256 tile, 8 waves, BK=32, 4-deep ring, R8 2-phase schedule =====
    // XCD-chunked bijective swizzle: 8 regions of 4by x 8bx (grid 256 = 16x16)
    int rg = rawb & 7, sq = rawb >> 3;
    int by = (rg >> 1) * 4 + (sq >> 3);
    int bx = (rg & 1) * 8 + (sq & 7);
    int rowBase = by * 256, colBase = bx * 256;
    int wr = wid >> 2, wc = wid & 3;
    int fr = lane & 15, g = lane >> 4;

    f32x4 acc[8][4];
    #pragma unroll
    for (int m = 0; m < 8; ++m)
        #pragma unroll
        for (int n = 0; n < 4; ++n) acc[m][n] = (f32x4){0.f, 0.f, 0.f, 0.f};

    int pcoff = ((g ^ ((fr >> 1) & 3)) * 8);
    int aoff = (wr * 128 + fr) * 32 + pcoff;
    int boff = 8192 + (wc * 64 + fr) * 32 + pcoff;

    stage_range(ldsAll, vhat, that_, rowBase, colBase, 0, 0, 3, wid, lane);
    stage_range(ldsAll, vhat, that_, rowBase, colBase, 1, 0, 3, wid, lane);
    stage_range(ldsAll, vhat, that_, rowBase, colBase, 2, 0, 3, wid, lane);
    WAITVM(8);
    __builtin_amdgcn_s_barrier();

    for (int T = 0; T < NKT; ++T) {
        const __hip_bfloat16* U = ldsAll + (T & 3) * 16384;
        // phase A: reads(a0,bb) || stage half1(T+3) -> BAR -> MFMA m0..3
        bf16x8 a0[4], bb[4];
        #pragma unroll
        for (int m = 0; m < 4; ++m) a0[m] = *(const bf16x8*)(U + aoff + m * 512);
        #pragma unroll
        for (int n = 0; n < 4; ++n) bb[n] = *(const bf16x8*)(U + boff + n * 512);
        if (T + 3 < NKT)
            stage_range(ldsAll, vhat, that_, rowBase, colBase, T + 3, 0, 1, wid, lane);
        __builtin_amdgcn_sched_barrier(0);
        __builtin_amdgcn_s_barrier();
        WAITLGKM0;
        __builtin_amdgcn_sched_barrier(0);
        __builtin_amdgcn_s_setprio(1);
        #pragma unroll
        for (int m = 0; m < 4; ++m)
            #pragma unroll
            for (int n = 0; n < 4; ++n)
                acc[m][n] = __builtin_amdgcn_mfma_f32_16x16x32_bf16(a0[m], bb[n], acc[m][n], 0, 0, 0);
        __builtin_amdgcn_s_setprio(0);
        __builtin_amdgcn_sched_barrier(0);
        __builtin_amdgcn_s_barrier();
        // phase B: reads(a1) || stage half2(T+3) -> BAR -> MFMA m4..7
        bf16x8 a1[4];
        #pragma unroll
        for (int m = 0; m < 4; ++m) a1[m] = *(const bf16x8*)(U + aoff + (m + 4) * 512);
        if (T + 3 < NKT)
            stage_range(ldsAll, vhat, that_, rowBase, colBase, T + 3, 2, 3, wid, lane);
        __builtin_amdgcn_sched_barrier(0);
        __builtin_amdgcn_s_barrier();
        WAITLGKM0;
        __builtin_amdgcn_sched_barrier(0);
        __builtin_amdgcn_s_setprio(1);
        #pragma unroll
        for (int m = 0; m < 4; ++m)
            #pragma unroll
            for (int n = 0; n < 4; ++n)
                acc[m + 4][n] = __builtin_amdgcn_mfma_f32_16x16x32_bf16(a1[m], bb[n], acc[m + 4][n], 0, 0, 0);
        __builtin_amdgcn_s_setprio(0);
        __builtin_amdgcn_sched_barrier(0);
        // tile boundary: T+1 staged; keep T+2/T+3 in flight (never vmcnt 0 mid-loop)
        if (T < NKT - 3)       { WAITVM(8); }
        else if (T == NKT - 3) { WAITVM(4); }
        else if (T == NKT - 2) { WAITVM(0); }
        __builtin_amdgcn_s_barrier();
    }

    // ===== stats: {total, S_mf, trace};  C/D: col=fr, row=g*4+reg [m89-verified] =====
    if (t < 256) idr[t] = ids[rowBase + t];
    else         idc[t - 256] = ids[colBase + (t - 256)];
    __syncthreads();
    {
        float tsum = 0.f, msum = 0.f, dsum = 0.f;
        #pragma unroll
        for (int m = 0; m < 8; ++m) {
            int rl = wr * 128 + m * 16 + g * 4;
            #pragma unroll
            for (int n = 0; n < 4; ++n) {
                int cl = wc * 64 + n * 16 + fr;
                int colId = idc[cl];
                int gj = colBase + cl;
                #pragma unroll
                for (int r = 0; r < 4; ++r) {
                    float val = acc[m][n][r];
                    tsum += val;
                    if (idr[rl + r] == colId) msum += val;
                    if (rowBase + rl + r == gj) dsum += val;
                }
            }
        }
        #pragma unroll
        for (int off = 32; off > 0; off >>= 1) {
            tsum += __shfl_down(tsum, off, 64);
            msum += __shfl_down(msum, off, 64);
            dsum += __shfl_down(dsum, off, 64);
        }
        if (lane == 0) { red[wid] = tsum; red[8 + wid] = msum; red[16 + wid] = dsum; }
        __syncthreads();
        if (t == 0) {
            float s0 = 0.f, s1 = 0.f, s2 = 0.f;
            #pragma unroll
            for (int w = 0; w < 8; ++w) { s0 += red[w]; s1 += red[8 + w]; s2 += red[16 + w]; }
            atomicAdd(&scal[0], s0);
            atomicAdd(&scal[1], s1);
            atomicAdd(&scal[2], s2);
        }
    }

    // ===== grid barrier #2: stats complete =====
    __syncthreads();
    if (t == 0) {
        __hip_atomic_fetch_add(bar, 1u, __ATOMIC_ACQ_REL, __HIP_MEMORY_SCOPE_AGENT);
        while (__hip_atomic_load(bar, __ATOMIC_ACQUIRE, __HIP_MEMORY_SCOPE_AGENT) < 2 * NBLK)
            __builtin_amdgcn_s_sleep(2);
    }
    __syncthreads();

    // ===== np reduce + invT (all blocks need it) =====
    {
        int myn = (t < NBLK) ? npart[t] : 0;
        #pragma unroll
        for (int off = 32; off > 0; off >>= 1) myn += __shfl_down(myn, off, 64);
        if (lane == 0) wred_i[wid] = myn;
        __syncthreads();
        if (t == 0) {
            int npi = 0;
            #pragma unroll
            for (int w = 0; w < 8; ++w) npi += wred_i[w];
            float total = __hip_atomic_load(&scal[0], __ATOMIC_RELAXED, __HIP_MEMORY_SCOPE_AGENT);
            float mf    = __hip_atomic_load(&scal[1], __ATOMIC_RELAXED, __HIP_MEMORY_SCOPE_AGENT);
            float trace = __hip_atomic_load(&scal[2], __ATOMIC_RELAXED, __HIP_MEMORY_SCOPE_AGENT);
            float np = (float)npi;
            float pos_cnt = np - (float)NB;
            float neg_cnt = (float)NB * (float)NB - np;
            float pos_mean = (mf - trace) / fmaxf(1.0f, pos_cnt);
            float neg_mean = (total - mf) / fmaxf(1.0f, neg_cnt);
            float sep = pos_mean - neg_mean;
            float temp = 0.07f * (0.8f + 0.4f * expf(-2.0f * sep));
            temp = fminf(fmaxf(temp, 0.04f), 0.2f);
            invT_sh = 1.0f / temp;
            mf_sh = mf;
        }
        if (t < 256) { rs_l[t] = 0.0f; cs_l[t] = 0.0f; }
        __syncthreads();
    }
    float invT = invT_sh;

    // ===== exp((sim-1)/temp) row & col sums straight from registers =====
    #pragma unroll
    for (int m = 0; m < 8; ++m)
        #pragma unroll
        for (int n = 0; n < 4; ++n)
            #pragma unroll
            for (int r = 0; r < 4; ++r)
                acc[m][n][r] = __expf((acc[m][n][r] - 1.0f) * invT);
    #pragma unroll
    for (int m = 0; m < 8; ++m) {
        #pragma unroll
        for (int r = 0; r < 4; ++r) {
            float rp = 0.f;
            #pragma unroll
            for (int n = 0; n < 4; ++n) rp += acc[m][n][r];
            rp += __shfl_xor(rp, 1, 64);
            rp += __shfl_xor(rp, 2, 64);
            rp += __shfl_xor(rp, 4, 64);
            rp += __shfl_xor(rp, 8, 64);
            if (fr == 0) atomicAdd(&rs_l[wr * 128 + m * 16 + g * 4 + r], rp);
        }
    }
    #pragma unroll
    for (int n = 0; n < 4; ++n) {
        float cp = 0.f;
        #pragma unroll
        for (int m = 0; m < 8; ++m)
            #pragma unroll
            for (int r = 0; r < 4; ++r) cp += acc[m][n][r];
        cp += __shfl_xor(cp, 16, 64);
        cp += __shfl_xor(cp, 32, 64);
        if (g == 0) atomicAdd(&cs_l[wc * 64 + n * 16 + fr], cp);
    }
    __syncthreads();
    if (t < 256) {
        atomicAdd(&rs[rowBase + t], rs_l[t]);
        atomicAdd(&cs[colBase + t], cs_l[t]);
    }

    // ===== barrier #3: all arrive; only block 0 spins and finishes =====
    __syncthreads();
    if (t == 0)
        __hip_atomic_fetch_add(bar, 1u, __ATOMIC_ACQ_REL, __HIP_MEMORY_SCOPE_AGENT);
    if (rawb != 0) return;
    if (t == 0) {
        while (__hip_atomic_load(bar, __ATOMIC_ACQUIRE, __HIP_MEMORY_SCOPE_AGENT) < 3 * NBLK)
            __builtin_amdgcn_s_sleep(2);
    }
    __syncthreads();

    // ===== final loss (block 0, 512 threads) =====
    {
        float a = 0.f, npl = 0.f;
        for (int i = t; i < NB; i += 512) {
            float cf = cntf[i];
            a += cf * (logf(rs[i]) + logf(cs[i]));
            npl += cf;
        }
        #pragma unroll
        for (int off = 32; off > 0; off >>= 1) {
            a += __shfl_down(a, off, 64);
            npl += __shfl_down(npl, off, 64);
        }
        if (lane == 0) { ra[wid] = a; rn[wid] = npl; }
        __syncthreads();
        if (t == 0) {
            float A = 0.f, np = 0.f;
            #pragma unroll
            for (int w = 0; w < 8; ++w) { A += ra[w]; np += rn[w]; }
            // lse_row[i] = 1/temp + log(rs[i]); v2t+t2v = sum cnt*(lse_r+lse_c) - 2*mf/temp
            out[0] = (A + 2.0f * invT_sh * (np - mf_sh)) / (2.0f * np);
        }
    }
}

extern "C" void kernel_launch(void* const* d_in, const int* in_sizes, int n_in,
                              void* d_out, int out_size, void* d_ws, size_t ws_size,
                              hipStream_t stream)
{
    const float* vf  = (const float*)d_in[0];
    const float* tf  = (const float*)d_in[1];
    const int*   ids = (const int*)d_in[2];

    float* ws_f = (float*)d_ws;
    float* scal = ws_f;                 // [0]=total [1]=S_mf [2]=trace [6]=bar
    float* rs   = ws_f + 16;            // 4096  (cs contiguous after rs — fused zeroes both via rs)
    float* cs   = ws_f + 16 + 4096;     // 4096
    float* cntf = ws_f + 16 + 8192;     // 4096
    int* npart  = (int*)(ws_f + 16 + 12288);   // 256 partial num_pos counts
    uint* bar   = (uint*)(scal + 6);
    __hip_bfloat16* vhat  = (__hip_bfloat16*)((char*)d_ws + 131072);
    __hip_bfloat16* that_ = vhat + (size_t)NB * DD;

    init_kernel<<<1, 64, 0, stream>>>(scal);
    fused_kernel<<<NBLK, 512, 0, stream>>>(vf, tf, ids, vhat, that_,
                                           scal, rs, cs, cntf, npart, bar, (float*)d_out);
}

// Round 12
// 91.052 us; speedup vs baseline: 1.3235x; 1.0014x over previous
//
#include <hip/hip_runtime.h>
#include <hip/hip_bf16.h>

#define NB 4096
#define DD 768
#define NKT 24            // K-tiles of BK=32: 768/32
#define NBLK 256          // grid: 256 blocks = 1 per CU (128KB LDS forces 1/CU) -> all co-resident

typedef __bf16 bf16x8 __attribute__((ext_vector_type(8)));
typedef float f32x4 __attribute__((ext_vector_type(4)));
typedef unsigned int uint;

#define WAITVM(N) asm volatile("s_waitcnt vmcnt(" #N ")" ::: "memory")

// ---------------- init: zero stats + grid-barrier counter (d_ws is poisoned 0xAA) ----------------
__global__ void init_kernel(float* scal)
{
    if (threadIdx.x < 16) scal[threadIdx.x] = 0.0f;
}

// ---------------- staging: one K-tile unit = A[256][32] + B[256][32] (32 KB) ----------------
// Swizzle (both sides, rule #21): logical chunk c (16B) of row r at phys chunk c ^ ((r>>1)&3).
// global_load_lds dest is linear (base+lane*16); lane's global source chunk = (lane&3)^((lane>>3)&3).
// Measured 0 bank conflicts (2-way aliasing = free, m136).
__device__ __forceinline__ void stage_range(
    __hip_bfloat16* ldsAll,
    const __hip_bfloat16* __restrict__ vhat, const __hip_bfloat16* __restrict__ that_,
    int rowBase, int colBase, int T, int i0, int i1, int wid, int lane)
{
    int u = T & 3;
    int k0 = T * 32;
    const __hip_bfloat16* src = (wid >= 4) ? that_ : vhat;
    int tb = (wid >= 4) ? colBase : rowBase;
    int w4 = wid & 3;
    int logc = (lane & 3) ^ ((lane >> 3) & 3);
    int rowIn = w4 * 64 + (lane >> 2);
    __hip_bfloat16* dbase = ldsAll + u * 16384 + ((wid >= 4) ? 8192 : 0) + w4 * 2048;
    #pragma unroll
    for (int i = i0; i <= i1; ++i) {
        const __hip_bfloat16* g = src + (size_t)(tb + rowIn + i * 16) * DD + k0 + logc * 8;
        __builtin_amdgcn_global_load_lds(
            (const __attribute__((address_space(1))) void*)g,
            (__attribute__((address_space(3))) void*)(dbase + i * 512),
            16, 0, 0);
    }
}

// ---------------- fully fused: normalize+cnt | bar1 | GEMM+stats | bar2 | exp sums | bar3 | loss ----------------
__global__ __launch_bounds__(512, 2) void fused_kernel(
    const float* __restrict__ vf, const float* __restrict__ tf, const int* __restrict__ ids,
    __hip_bfloat16* __restrict__ vhat, __hip_bfloat16* __restrict__ that_,
    float* scal, float* rs, float* cs, float* cntf, int* npart, uint* bar,
    float* __restrict__ out)
{
    __shared__ __hip_bfloat16 ldsAll[4 * 16384];   // 128 KB: ring units; reused as ids stage in phase 0
    __shared__ int idr[256], idc[256];
    __shared__ float red[24];
    __shared__ float rs_l[256], cs_l[256];
    __shared__ int bp[16], wred_i[8];
    __shared__ float ra[8], rn[8];
    __shared__ float invT_sh, mf_sh;

    int rawb = blockIdx.x;
    int t = threadIdx.x, wid = t >> 6, lane = t & 63;

    // ===== phase 0a: normalize 32 rows/block, 4 rows/wave, loads issued up-front =====
    {
        f32x4 xr[4][3];
        __hip_bfloat16* dsts[4];
        #pragma unroll
        for (int it = 0; it < 4; ++it) {
            int row = rawb * 32 + wid * 4 + it;
            const float* src;
            if (row < NB) { src = vf + (size_t)row * DD; dsts[it] = vhat + (size_t)row * DD; }
            else          { src = tf + (size_t)(row - NB) * DD; dsts[it] = that_ + (size_t)(row - NB) * DD; }
            xr[it][0] = __builtin_nontemporal_load((const f32x4*)(src + lane * 4));
            xr[it][1] = __builtin_nontemporal_load((const f32x4*)(src + 256 + lane * 4));
            xr[it][2] = __builtin_nontemporal_load((const f32x4*)(src + 512 + lane * 4));
        }
        int idreg[8];
        #pragma unroll
        for (int i = 0; i < 8; ++i) idreg[i] = ids[t + i * 512];

        #pragma unroll
        for (int it = 0; it < 4; ++it) {
            float s = 0.f;
            #pragma unroll
            for (int c = 0; c < 3; ++c)
                s += xr[it][c][0]*xr[it][c][0] + xr[it][c][1]*xr[it][c][1]
                   + xr[it][c][2]*xr[it][c][2] + xr[it][c][3]*xr[it][c][3];
            #pragma unroll
            for (int off = 1; off < 64; off <<= 1) s += __shfl_xor(s, off, 64);
            float scale = 1.0f / sqrtf(s);
            unsigned short* dsh = (unsigned short*)dsts[it];
            #pragma unroll
            for (int c = 0; c < 3; ++c) {
                ushort4 o;
                o.x = __builtin_bit_cast(unsigned short, __float2bfloat16(xr[it][c][0] * scale));
                o.y = __builtin_bit_cast(unsigned short, __float2bfloat16(xr[it][c][1] * scale));
                o.z = __builtin_bit_cast(unsigned short, __float2bfloat16(xr[it][c][2] * scale));
                o.w = __builtin_bit_cast(unsigned short, __float2bfloat16(xr[it][c][3] * scale));
                *(ushort4*)(dsh + c * 256 + lane * 4) = o;
            }
        }
        int* idsh = (int*)ldsAll;
        #pragma unroll
        for (int i = 0; i < 8; ++i) idsh[t + i * 512] = idreg[i];
    }
    __syncthreads();

    // ===== phase 0b: cnt — 32 lanes per id, int4 LDS scan =====
    {
        int* idsh = (int*)ldsAll;
        int sub = t >> 5, l32 = t & 31;
        int my = idsh[rawb * 16 + sub];
        const int4* idsh4 = (const int4*)idsh;
        int c = 0;
        #pragma unroll 8
        for (int j = l32; j < NB / 4; j += 32) {
            int4 v = idsh4[j];
            c += (v.x == my) + (v.y == my) + (v.z == my) + (v.w == my);
        }
        #pragma unroll
        for (int off = 16; off > 0; off >>= 1) c += __shfl_down(c, off, 32);
        if (l32 == 0) { cntf[rawb * 16 + sub] = (float)c; bp[sub] = c; }
    }
    // ===== phase 0c: zero rs+cs (contiguous 8192 floats starting at rs) =====
    if (t < 32) rs[rawb * 32 + t] = 0.0f;
    __syncthreads();
    if (t == 0) {
        int s = 0;
        #pragma unroll
        for (int i = 0; i < 16; ++i) s += bp[i];
        npart[rawb] = s;
    }

    // ===== grid barrier #1: vhat/that/cntf/npart/rs-zero published =====
    __syncthreads();
    if (t == 0) {
        __hip_atomic_fetch_add(bar, 1u, __ATOMIC_ACQ_REL, __HIP_MEMORY_SCOPE_AGENT);
        while (__hip_atomic_load(bar, __ATOMIC_ACQUIRE, __HIP_MEMORY_SCOPE_AGENT) < NBLK)
            __builtin_amdgcn_s_sleep(2);
    }
    __syncthreads();

    // ===== GEMM: 256x256 tile, 8 waves, BK=32, 4-deep ring, 2-phase, NO lgkm walls =====
    // (compiler emits counted lgkmcnt so MFMA overlaps ds_read tail — m97 evidence)
    int rg = rawb & 7, sq = rawb >> 3;
    int by = (rg >> 1) * 4 + (sq >> 3);
    int bx = (rg & 1) * 8 + (sq & 7);
    int rowBase = by * 256, colBase = bx * 256;
    int wr = wid >> 2, wc = wid & 3;
    int fr = lane & 15, g = lane >> 4;

    f32x4 acc[8][4];
    #pragma unroll
    for (int m = 0; m < 8; ++m)
        #pragma unroll
        for (int n = 0; n < 4; ++n) acc[m][n] = (f32x4){0.f, 0.f, 0.f, 0.f};

    int pcoff = ((g ^ ((fr >> 1) & 3)) * 8);
    int aoff = (wr * 128 + fr) * 32 + pcoff;
    int boff = 8192 + (wc * 64 + fr) * 32 + pcoff;

    stage_range(ldsAll, vhat, that_, rowBase, colBase, 0, 0, 3, wid, lane);
    stage_range(ldsAll, vhat, that_, rowBase, colBase, 1, 0, 3, wid, lane);
    stage_range(ldsAll, vhat, that_, rowBase, colBase, 2, 0, 3, wid, lane);
    WAITVM(8);
    __builtin_amdgcn_s_barrier();

    for (int T = 0; T < NKT; ++T) {
        const __hip_bfloat16* U = ldsAll + (T & 3) * 16384;
        // phase A: reads(a0,bb) || stage half1(T+3) -> BAR -> MFMA m0..3 (counted lgkm by compiler)
        bf16x8 a0[4], bb[4];
        #pragma unroll
        for (int m = 0; m < 4; ++m) a0[m] = *(const bf16x8*)(U + aoff + m * 512);
        #pragma unroll
        for (int n = 0; n < 4; ++n) bb[n] = *(const bf16x8*)(U + boff + n * 512);
        if (T + 3 < NKT)
            stage_range(ldsAll, vhat, that_, rowBase, colBase, T + 3, 0, 1, wid, lane);
        __builtin_amdgcn_s_barrier();
        __builtin_amdgcn_s_setprio(1);
        #pragma unroll
        for (int m = 0; m < 4; ++m)
            #pragma unroll
            for (int n = 0; n < 4; ++n)
                acc[m][n] = __builtin_amdgcn_mfma_f32_16x16x32_bf16(a0[m], bb[n], acc[m][n], 0, 0, 0);
        __builtin_amdgcn_s_setprio(0);
        __builtin_amdgcn_s_barrier();
        // phase B: reads(a1) || stage half2(T+3) -> BAR -> MFMA m4..7
        bf16x8 a1[4];
        #pragma unroll
        for (int m = 0; m < 4; ++m) a1[m] = *(const bf16x8*)(U + aoff + (m + 4) * 512);
        if (T + 3 < NKT)
            stage_range(ldsAll, vhat, that_, rowBase, colBase, T + 3, 2, 3, wid, lane);
        __builtin_amdgcn_s_barrier();
        __builtin_amdgcn_s_setprio(1);
        #pragma unroll
        for (int m = 0; m < 4; ++m)
            #pragma unroll
            for (int n = 0; n < 4; ++n)
                acc[m + 4][n] = __builtin_amdgcn_mfma_f32_16x16x32_bf16(a1[m], bb[n], acc[m + 4][n], 0, 0, 0);
        __builtin_amdgcn_s_setprio(0);
        // tile boundary: T+1 staged; keep T+2/T+3 in flight (never vmcnt 0 mid-loop)
        if (T < NKT - 3)       { WAITVM(8); }
        else if (T == NKT - 3) { WAITVM(4); }
        else if (T == NKT - 2) { WAITVM(0); }
        __builtin_amdgcn_s_barrier();
    }

    // ===== stats: {total, S_mf, trace};  C/D: col=fr, row=g*4+reg [m89-verified] =====
    if (t < 256) idr[t] = ids[rowBase + t];
    else         idc[t - 256] = ids[colBase + (t - 256)];
    __syncthreads();
    {
        float tsum = 0.f, msum = 0.f, dsum = 0.f;
        #pragma unroll
        for (int m = 0; m < 8; ++m) {
            int rl = wr * 128 + m * 16 + g * 4;
            #pragma unroll
            for (int n = 0; n < 4; ++n) {
                int cl = wc * 64 + n * 16 + fr;
                int colId = idc[cl];
                int gj = colBase + cl;
                #pragma unroll
                for (int r = 0; r < 4; ++r) {
                    float val = acc[m][n][r];
                    tsum += val;
                    if (idr[rl + r] == colId) msum += val;
                    if (rowBase + rl + r == gj) dsum += val;
                }
            }
        }
        #pragma unroll
        for (int off = 32; off > 0; off >>= 1) {
            tsum += __shfl_down(tsum, off, 64);
            msum += __shfl_down(msum, off, 64);
            dsum += __shfl_down(dsum, off, 64);
        }
        if (lane == 0) { red[wid] = tsum; red[8 + wid] = msum; red[16 + wid] = dsum; }
        __syncthreads();
        if (t == 0) {
            float s0 = 0.f, s1 = 0.f, s2 = 0.f;
            #pragma unroll
            for (int w = 0; w < 8; ++w) { s0 += red[w]; s1 += red[8 + w]; s2 += red[16 + w]; }
            atomicAdd(&scal[0], s0);
            atomicAdd(&scal[1], s1);
            atomicAdd(&scal[2], s2);
        }
    }

    // ===== grid barrier #2: stats complete =====
    __syncthreads();
    if (t == 0) {
        __hip_atomic_fetch_add(bar, 1u, __ATOMIC_ACQ_REL, __HIP_MEMORY_SCOPE_AGENT);
        while (__hip_atomic_load(bar, __ATOMIC_ACQUIRE, __HIP_MEMORY_SCOPE_AGENT) < 2 * NBLK)
            __builtin_amdgcn_s_sleep(2);
    }
    __syncthreads();

    // ===== np reduce + invT (all blocks need it) =====
    {
        int myn = (t < NBLK) ? npart[t] : 0;
        #pragma unroll
        for (int off = 32; off > 0; off >>= 1) myn += __shfl_down(myn, off, 64);
        if (lane == 0) wred_i[wid] = myn;
        __syncthreads();
        if (t == 0) {
            int npi = 0;
            #pragma unroll
            for (int w = 0; w < 8; ++w) npi += wred_i[w];
            float total = __hip_atomic_load(&scal[0], __ATOMIC_RELAXED, __HIP_MEMORY_SCOPE_AGENT);
            float mf    = __hip_atomic_load(&scal[1], __ATOMIC_RELAXED, __HIP_MEMORY_SCOPE_AGENT);
            float trace = __hip_atomic_load(&scal[2], __ATOMIC_RELAXED, __HIP_MEMORY_SCOPE_AGENT);
            float np = (float)npi;
            float pos_cnt = np - (float)NB;
            float neg_cnt = (float)NB * (float)NB - np;
            float pos_mean = (mf - trace) / fmaxf(1.0f, pos_cnt);
            float neg_mean = (total - mf) / fmaxf(1.0f, neg_cnt);
            float sep = pos_mean - neg_mean;
            float temp = 0.07f * (0.8f + 0.4f * expf(-2.0f * sep));
            temp = fminf(fmaxf(temp, 0.04f), 0.2f);
            invT_sh = 1.0f / temp;
            mf_sh = mf;
        }
        if (t < 256) { rs_l[t] = 0.0f; cs_l[t] = 0.0f; }
        __syncthreads();
    }
    float invT = invT_sh;

    // ===== exp((sim-1)/temp) row & col sums straight from registers =====
    #pragma unroll
    for (int m = 0; m < 8; ++m)
        #pragma unroll
        for (int n = 0; n < 4; ++n)
            #pragma unroll
            for (int r = 0; r < 4; ++r)
                acc[m][n][r] = __expf((acc[m][n][r] - 1.0f) * invT);
    #pragma unroll
    for (int m = 0; m < 8; ++m) {
        #pragma unroll
        for (int r = 0; r < 4; ++r) {
            float rp = 0.f;
            #pragma unroll
            for (int n = 0; n < 4; ++n) rp += acc[m][n][r];
            rp += __shfl_xor(rp, 1, 64);
            rp += __shfl_xor(rp, 2, 64);
            rp += __shfl_xor(rp, 4, 64);
            rp += __shfl_xor(rp, 8, 64);
            if (fr == 0) atomicAdd(&rs_l[wr * 128 + m * 16 + g * 4 + r], rp);
        }
    }
    #pragma unroll
    for (int n = 0; n < 4; ++n) {
        float cp = 0.f;
        #pragma unroll
        for (int m = 0; m < 8; ++m)
            #pragma unroll
            for (int r = 0; r < 4; ++r) cp += acc[m][n][r];
        cp += __shfl_xor(cp, 16, 64);
        cp += __shfl_xor(cp, 32, 64);
        if (g == 0) atomicAdd(&cs_l[wc * 64 + n * 16 + fr], cp);
    }
    __syncthreads();
    if (t < 256) {
        atomicAdd(&rs[rowBase + t], rs_l[t]);
        atomicAdd(&cs[colBase + t], cs_l[t]);
    }

    // ===== barrier #3: all arrive; only block 0 spins and finishes =====
    __syncthreads();
    if (t == 0)
        __hip_atomic_fetch_add(bar, 1u, __ATOMIC_ACQ_REL, __HIP_MEMORY_SCOPE_AGENT);
    if (rawb != 0) return;
    if (t == 0) {
        while (__hip_atomic_load(bar, __ATOMIC_ACQUIRE, __HIP_MEMORY_SCOPE_AGENT) < 3 * NBLK)
            __builtin_amdgcn_s_sleep(2);
    }
    __syncthreads();

    // ===== final loss (block 0, 512 threads) =====
    {
        float a = 0.f, npl = 0.f;
        for (int i = t; i < NB; i += 512) {
            float cf = cntf[i];
            a += cf * (logf(rs[i]) + logf(cs[i]));
            npl += cf;
        }
        #pragma unroll
        for (int off = 32; off > 0; off >>= 1) {
            a += __shfl_down(a, off, 64);
            npl += __shfl_down(npl, off, 64);
        }
        if (lane == 0) { ra[wid] = a; rn[wid] = npl; }
        __syncthreads();
        if (t == 0) {
            float A = 0.f, np = 0.f;
            #pragma unroll
            for (int w = 0; w < 8; ++w) { A += ra[w]; np += rn[w]; }
            // lse_row[i] = 1/temp + log(rs[i]); v2t+t2v = sum cnt*(lse_r+lse_c) - 2*mf/temp
            out[0] = (A + 2.0f * invT_sh * (np - mf_sh)) / (2.0f * np);
        }
    }
}

extern "C" void kernel_launch(void* const* d_in, const int* in_sizes, int n_in,
                              void* d_out, int out_size, void* d_ws, size_t ws_size,
                              hipStream_t stream)
{
    const float* vf  = (const float*)d_in[0];
    const float* tf  = (const float*)d_in[1];
    const int*   ids = (const int*)d_in[2];

    float* ws_f = (float*)d_ws;
    float* scal = ws_f;                 // [0]=total [1]=S_mf [2]=trace [6]=bar
    float* rs   = ws_f + 16;            // 4096  (cs contiguous after rs — fused zeroes both via rs)
    float* cs   = ws_f + 16 + 4096;     // 4096
    float* cntf = ws_f + 16 + 8192;     // 4096
    int* npart  = (int*)(ws_f + 16 + 12288);   // 256 partial num_pos counts
    uint* bar   = (uint*)(scal + 6);
    __hip_bfloat16* vhat  = (__hip_bfloat16*)((char*)d_ws + 131072);
    __hip_bfloat16* that_ = vhat + (size_t)NB * DD;

    init_kernel<<<1, 64, 0, stream>>>(scal);
    fused_kernel<<<NBLK, 512, 0, stream>>>(vf, tf, ids, vhat, that_,
                                           scal, rs, cs, cntf, npart, bar, (float*)d_out);
}

// Round 13
// 85.095 us; speedup vs baseline: 1.4162x; 1.0700x over previous
//
#include <hip/hip_runtime.h>
#include <hip/hip_bf16.h>

#define NB 4096
#define DD 768
#define NKT 12            // K-tiles of BK=64 (fp8): 768/64
#define NBLK 256          // grid: 256 blocks = 1 per CU (128KB LDS) -> all co-resident

typedef float f32x4 __attribute__((ext_vector_type(4)));
typedef long i64x2 __attribute__((ext_vector_type(2)));
typedef unsigned int uint;

#define WAITVM(N) asm volatile("s_waitcnt vmcnt(" #N ")" ::: "memory")

// ---------------- init: zero stats + grid-barrier counter (d_ws is poisoned 0xAA) ----------------
__global__ void init_kernel(float* scal)
{
    if (threadIdx.x < 16) scal[threadIdx.x] = 0.0f;
}

// ---------------- staging: one K-tile unit = A[256][64B] + B[256][64B] fp8 (32 KB), ring-4 ----------------
// Rows are 64 B (4 chunks of 16 B) — same swizzle as the verified bf16 BK=32 scheme:
// logical chunk c of row r at phys chunk c ^ ((r>>1)&3); linear LDS dest, pre-swizzled global
// source chunk = (lane&3) ^ ((lane>>3)&3) (rule #21). Measured 0 bank conflicts.
__device__ __forceinline__ void stage_range(
    unsigned char* ldsAll,
    const unsigned char* __restrict__ vhat8, const unsigned char* __restrict__ that8,
    int rowBase, int colBase, int T, int i0, int i1, int wid, int lane)
{
    int u = T & 3;
    const unsigned char* src = (wid >= 4) ? that8 : vhat8;
    int tb = (wid >= 4) ? colBase : rowBase;
    int w4 = wid & 3;
    int logc = (lane & 3) ^ ((lane >> 3) & 3);
    int rowIn = w4 * 64 + (lane >> 2);
    unsigned char* dbase = ldsAll + u * 32768 + ((wid >= 4) ? 16384 : 0) + w4 * 4096;
    #pragma unroll
    for (int i = i0; i <= i1; ++i) {
        const unsigned char* g = src + (size_t)(tb + rowIn + i * 16) * DD + T * 64 + logc * 16;
        __builtin_amdgcn_global_load_lds(
            (const __attribute__((address_space(1))) void*)g,
            (__attribute__((address_space(3))) void*)(dbase + i * 1024),
            16, 0, 0);
    }
}

// ---------------- fully fused: normalize->fp8 + cnt | bar1 | GEMM+stats | bar2 | exp sums | bar3 | loss ----------------
__global__ __launch_bounds__(512, 2) void fused_kernel(
    const float* __restrict__ vf, const float* __restrict__ tf, const int* __restrict__ ids,
    unsigned char* __restrict__ vhat8, unsigned char* __restrict__ that8,
    float* scal, float* rs, float* cs, float* cntf, int* npart, uint* bar,
    float* __restrict__ out)
{
    __shared__ unsigned char ldsAll[4 * 32768];   // 128 KB ring; reused as ids stage in phase 0
    __shared__ int idr[256], idc[256];
    __shared__ float red[24];
    __shared__ float rs_l[256], cs_l[256];
    __shared__ int bp[16], wred_i[8];
    __shared__ float ra[8], rn[8];
    __shared__ float invT_sh, mf_sh;

    int rawb = blockIdx.x;
    int t = threadIdx.x, wid = t >> 6, lane = t & 63;

    // ===== phase 0a: normalize 32 rows/block -> fp8 e4m3 in MFMA-chunk-interleaved layout =====
    // Global fp8 layout per row: byte pos = t64*64 + g*16 + kh*8 + e for original k = t64*64 + kh*32 + g*8 + e.
    // (k-permutations are dot-product-exact as long as A and B use the same map — they do.)
    {
        f32x4 xr[4][3];
        uint* dsts[4];
        #pragma unroll
        for (int it = 0; it < 4; ++it) {
            int row = rawb * 32 + wid * 4 + it;
            const float* src;
            if (row < NB) { src = vf + (size_t)row * DD; dsts[it] = (uint*)(vhat8 + (size_t)row * DD); }
            else          { src = tf + (size_t)(row - NB) * DD; dsts[it] = (uint*)(that8 + (size_t)(row - NB) * DD); }
            xr[it][0] = __builtin_nontemporal_load((const f32x4*)(src + lane * 4));
            xr[it][1] = __builtin_nontemporal_load((const f32x4*)(src + 256 + lane * 4));
            xr[it][2] = __builtin_nontemporal_load((const f32x4*)(src + 512 + lane * 4));
        }
        int idreg[8];
        #pragma unroll
        for (int i = 0; i < 8; ++i) idreg[i] = ids[t + i * 512];

        #pragma unroll
        for (int it = 0; it < 4; ++it) {
            float s = 0.f;
            #pragma unroll
            for (int c = 0; c < 3; ++c)
                s += xr[it][c][0]*xr[it][c][0] + xr[it][c][1]*xr[it][c][1]
                   + xr[it][c][2]*xr[it][c][2] + xr[it][c][3]*xr[it][c][3];
            #pragma unroll
            for (int off = 1; off < 64; off <<= 1) s += __shfl_xor(s, off, 64);
            float scale = 1.0f / sqrtf(s);
            #pragma unroll
            for (int c = 0; c < 3; ++c) {
                int k0 = c * 256 + lane * 4;
                int dw = (k0 >> 6) * 16 + (((k0 >> 3) & 3) << 2)
                       + (((k0 >> 5) & 1) << 1) + ((k0 & 7) >> 2);
                int p = __builtin_amdgcn_cvt_pk_fp8_f32(xr[it][c][0] * scale, xr[it][c][1] * scale, 0, false);
                p = __builtin_amdgcn_cvt_pk_fp8_f32(xr[it][c][2] * scale, xr[it][c][3] * scale, p, true);
                dsts[it][dw] = (uint)p;
            }
        }
        int* idsh = (int*)ldsAll;
        #pragma unroll
        for (int i = 0; i < 8; ++i) idsh[t + i * 512] = idreg[i];
    }
    __syncthreads();

    // ===== phase 0b: cnt — 32 lanes per id, int4 LDS scan =====
    {
        int* idsh = (int*)ldsAll;
        int sub = t >> 5, l32 = t & 31;
        int my = idsh[rawb * 16 + sub];
        const int4* idsh4 = (const int4*)idsh;
        int c = 0;
        #pragma unroll 8
        for (int j = l32; j < NB / 4; j += 32) {
            int4 v = idsh4[j];
            c += (v.x == my) + (v.y == my) + (v.z == my) + (v.w == my);
        }
        #pragma unroll
        for (int off = 16; off > 0; off >>= 1) c += __shfl_down(c, off, 32);
        if (l32 == 0) { cntf[rawb * 16 + sub] = (float)c; bp[sub] = c; }
    }
    // ===== phase 0c: zero rs+cs (contiguous 8192 floats starting at rs) =====
    if (t < 32) rs[rawb * 32 + t] = 0.0f;
    __syncthreads();
    if (t == 0) {
        int s = 0;
        #pragma unroll
        for (int i = 0; i < 16; ++i) s += bp[i];
        npart[rawb] = s;
    }

    // ===== grid barrier #1: vhat8/that8/cntf/npart/rs-zero published =====
    __syncthreads();
    if (t == 0) {
        __hip_atomic_fetch_add(bar, 1u, __ATOMIC_ACQ_REL, __HIP_MEMORY_SCOPE_AGENT);
        while (__hip_atomic_load(bar, __ATOMIC_ACQUIRE, __HIP_MEMORY_SCOPE_AGENT) < NBLK)
            __builtin_amdgcn_s_sleep(2);
    }
    __syncthreads();

    // ===== GEMM: 256x256 tile, 8 waves, fp8 BK=64, ring-4, 2-phase =====
    int rg = rawb & 7, sq = rawb >> 3;
    int by = (rg >> 1) * 4 + (sq >> 3);
    int bx = (rg & 1) * 8 + (sq & 7);
    int rowBase = by * 256, colBase = bx * 256;
    int wr = wid >> 2, wc = wid & 3;
    int fr = lane & 15, g = lane >> 4;

    f32x4 acc[8][4];
    #pragma unroll
    for (int m = 0; m < 8; ++m)
        #pragma unroll
        for (int n = 0; n < 4; ++n) acc[m][n] = (f32x4){0.f, 0.f, 0.f, 0.f};

    // byte offsets: phys chunk = g ^ ((row>>1)&3); one b128 read = {kh0 8B, kh1 8B} for group g
    int pcoff = (g ^ ((fr >> 1) & 3)) * 16;
    int aoffB = (wr * 128 + fr) * 64 + pcoff;
    int boffB = 16384 + (wc * 64 + fr) * 64 + pcoff;

    stage_range(ldsAll, vhat8, that8, rowBase, colBase, 0, 0, 3, wid, lane);
    stage_range(ldsAll, vhat8, that8, rowBase, colBase, 1, 0, 3, wid, lane);
    stage_range(ldsAll, vhat8, that8, rowBase, colBase, 2, 0, 3, wid, lane);
    WAITVM(8);
    __builtin_amdgcn_s_barrier();

    // Ledger (identical to verified bf16 version): at boundary of T, in flight = T+1(4)+T+2(4)+T+3(4);
    // WAITVM(8) retires tile T+1. stage(T+3) writes unit (T-1)&3, reads of which completed last iter.
    for (int T = 0; T < NKT; ++T) {
        const unsigned char* U = ldsAll + (T & 3) * 32768;
        // phase A: reads(a0,bb) || stage half1(T+3) -> BAR -> MFMA m0..3 (x2 k-halves)
        i64x2 a0[4], bb[4];
        #pragma unroll
        for (int m = 0; m < 4; ++m) a0[m] = *(const i64x2*)(U + aoffB + m * 1024);
        #pragma unroll
        for (int n = 0; n < 4; ++n) bb[n] = *(const i64x2*)(U + boffB + n * 1024);
        if (T + 3 < NKT)
            stage_range(ldsAll, vhat8, that8, rowBase, colBase, T + 3, 0, 1, wid, lane);
        __builtin_amdgcn_s_barrier();
        __builtin_amdgcn_s_setprio(1);
        #pragma unroll
        for (int m = 0; m < 4; ++m)
            #pragma unroll
            for (int n = 0; n < 4; ++n) {
                acc[m][n] = __builtin_amdgcn_mfma_f32_16x16x32_fp8_fp8(a0[m][0], bb[n][0], acc[m][n], 0, 0, 0);
                acc[m][n] = __builtin_amdgcn_mfma_f32_16x16x32_fp8_fp8(a0[m][1], bb[n][1], acc[m][n], 0, 0, 0);
            }
        __builtin_amdgcn_s_setprio(0);
        __builtin_amdgcn_s_barrier();
        // phase B: reads(a1) || stage half2(T+3) -> BAR -> MFMA m4..7
        i64x2 a1[4];
        #pragma unroll
        for (int m = 0; m < 4; ++m) a1[m] = *(const i64x2*)(U + aoffB + (m + 4) * 1024);
        if (T + 3 < NKT)
            stage_range(ldsAll, vhat8, that8, rowBase, colBase, T + 3, 2, 3, wid, lane);
        __builtin_amdgcn_s_barrier();
        __builtin_amdgcn_s_setprio(1);
        #pragma unroll
        for (int m = 0; m < 4; ++m)
            #pragma unroll
            for (int n = 0; n < 4; ++n) {
                acc[m + 4][n] = __builtin_amdgcn_mfma_f32_16x16x32_fp8_fp8(a1[m][0], bb[n][0], acc[m + 4][n], 0, 0, 0);
                acc[m + 4][n] = __builtin_amdgcn_mfma_f32_16x16x32_fp8_fp8(a1[m][1], bb[n][1], acc[m + 4][n], 0, 0, 0);
            }
        __builtin_amdgcn_s_setprio(0);
        // tile boundary: T+1 staged; keep T+2/T+3 in flight (never vmcnt 0 mid-loop)
        if (T < NKT - 3)       { WAITVM(8); }
        else if (T == NKT - 3) { WAITVM(4); }
        else if (T == NKT - 2) { WAITVM(0); }
        __builtin_amdgcn_s_barrier();
    }

    // ===== stats: {total, S_mf, trace};  C/D: col=fr, row=g*4+reg [m89-verified, dtype-independent] =====
    if (t < 256) idr[t] = ids[rowBase + t];
    else         idc[t - 256] = ids[colBase + (t - 256)];
    __syncthreads();
    {
        float tsum = 0.f, msum = 0.f, dsum = 0.f;
        #pragma unroll
        for (int m = 0; m < 8; ++m) {
            int rl = wr * 128 + m * 16 + g * 4;
            #pragma unroll
            for (int n = 0; n < 4; ++n) {
                int cl = wc * 64 + n * 16 + fr;
                int colId = idc[cl];
                int gj = colBase + cl;
                #pragma unroll
                for (int r = 0; r < 4; ++r) {
                    float val = acc[m][n][r];
                    tsum += val;
                    if (idr[rl + r] == colId) msum += val;
                    if (rowBase + rl + r == gj) dsum += val;
                }
            }
        }
        #pragma unroll
        for (int off = 32; off > 0; off >>= 1) {
            tsum += __shfl_down(tsum, off, 64);
            msum += __shfl_down(msum, off, 64);
            dsum += __shfl_down(dsum, off, 64);
        }
        if (lane == 0) { red[wid] = tsum; red[8 + wid] = msum; red[16 + wid] = dsum; }
        __syncthreads();
        if (t == 0) {
            float s0 = 0.f, s1 = 0.f, s2 = 0.f;
            #pragma unroll
            for (int w = 0; w < 8; ++w) { s0 += red[w]; s1 += red[8 + w]; s2 += red[16 + w]; }
            atomicAdd(&scal[0], s0);
            atomicAdd(&scal[1], s1);
            atomicAdd(&scal[2], s2);
        }
    }

    // ===== grid barrier #2: stats complete =====
    __syncthreads();
    if (t == 0) {
        __hip_atomic_fetch_add(bar, 1u, __ATOMIC_ACQ_REL, __HIP_MEMORY_SCOPE_AGENT);
        while (__hip_atomic_load(bar, __ATOMIC_ACQUIRE, __HIP_MEMORY_SCOPE_AGENT) < 2 * NBLK)
            __builtin_amdgcn_s_sleep(2);
    }
    __syncthreads();

    // ===== np reduce + invT =====
    {
        int myn = (t < NBLK) ? npart[t] : 0;
        #pragma unroll
        for (int off = 32; off > 0; off >>= 1) myn += __shfl_down(myn, off, 64);
        if (lane == 0) wred_i[wid] = myn;
        __syncthreads();
        if (t == 0) {
            int npi = 0;
            #pragma unroll
            for (int w = 0; w < 8; ++w) npi += wred_i[w];
            float total = __hip_atomic_load(&scal[0], __ATOMIC_RELAXED, __HIP_MEMORY_SCOPE_AGENT);
            float mf    = __hip_atomic_load(&scal[1], __ATOMIC_RELAXED, __HIP_MEMORY_SCOPE_AGENT);
            float trace = __hip_atomic_load(&scal[2], __ATOMIC_RELAXED, __HIP_MEMORY_SCOPE_AGENT);
            float np = (float)npi;
            float pos_cnt = np - (float)NB;
            float neg_cnt = (float)NB * (float)NB - np;
            float pos_mean = (mf - trace) / fmaxf(1.0f, pos_cnt);
            float neg_mean = (total - mf) / fmaxf(1.0f, neg_cnt);
            float sep = pos_mean - neg_mean;
            float temp = 0.07f * (0.8f + 0.4f * expf(-2.0f * sep));
            temp = fminf(fmaxf(temp, 0.04f), 0.2f);
            invT_sh = 1.0f / temp;
            mf_sh = mf;
        }
        if (t < 256) { rs_l[t] = 0.0f; cs_l[t] = 0.0f; }
        __syncthreads();
    }
    float invT = invT_sh;

    // ===== exp((sim-1)/temp) row & col sums straight from registers =====
    #pragma unroll
    for (int m = 0; m < 8; ++m)
        #pragma unroll
        for (int n = 0; n < 4; ++n)
            #pragma unroll
            for (int r = 0; r < 4; ++r)
                acc[m][n][r] = __expf((acc[m][n][r] - 1.0f) * invT);
    #pragma unroll
    for (int m = 0; m < 8; ++m) {
        #pragma unroll
        for (int r = 0; r < 4; ++r) {
            float rp = 0.f;
            #pragma unroll
            for (int n = 0; n < 4; ++n) rp += acc[m][n][r];
            rp += __shfl_xor(rp, 1, 64);
            rp += __shfl_xor(rp, 2, 64);
            rp += __shfl_xor(rp, 4, 64);
            rp += __shfl_xor(rp, 8, 64);
            if (fr == 0) atomicAdd(&rs_l[wr * 128 + m * 16 + g * 4 + r], rp);
        }
    }
    #pragma unroll
    for (int n = 0; n < 4; ++n) {
        float cp = 0.f;
        #pragma unroll
        for (int m = 0; m < 8; ++m)
            #pragma unroll
            for (int r = 0; r < 4; ++r) cp += acc[m][n][r];
        cp += __shfl_xor(cp, 16, 64);
        cp += __shfl_xor(cp, 32, 64);
        if (g == 0) atomicAdd(&cs_l[wc * 64 + n * 16 + fr], cp);
    }
    __syncthreads();
    if (t < 256) {
        atomicAdd(&rs[rowBase + t], rs_l[t]);
        atomicAdd(&cs[colBase + t], cs_l[t]);
    }

    // ===== barrier #3: all arrive; only block 0 spins and finishes =====
    __syncthreads();
    if (t == 0)
        __hip_atomic_fetch_add(bar, 1u, __ATOMIC_ACQ_REL, __HIP_MEMORY_SCOPE_AGENT);
    if (rawb != 0) return;
    if (t == 0) {
        while (__hip_atomic_load(bar, __ATOMIC_ACQUIRE, __HIP_MEMORY_SCOPE_AGENT) < 3 * NBLK)
            __builtin_amdgcn_s_sleep(2);
    }
    __syncthreads();

    // ===== final loss (block 0, 512 threads) =====
    {
        float a = 0.f, npl = 0.f;
        for (int i = t; i < NB; i += 512) {
            float cf = cntf[i];
            a += cf * (logf(rs[i]) + logf(cs[i]));
            npl += cf;
        }
        #pragma unroll
        for (int off = 32; off > 0; off >>= 1) {
            a += __shfl_down(a, off, 64);
            npl += __shfl_down(npl, off, 64);
        }
        if (lane == 0) { ra[wid] = a; rn[wid] = npl; }
        __syncthreads();
        if (t == 0) {
            float A = 0.f, np = 0.f;
            #pragma unroll
            for (int w = 0; w < 8; ++w) { A += ra[w]; np += rn[w]; }
            // lse_row[i] = 1/temp + log(rs[i]); v2t+t2v = sum cnt*(lse_r+lse_c) - 2*mf/temp
            out[0] = (A + 2.0f * invT_sh * (np - mf_sh)) / (2.0f * np);
        }
    }
}

extern "C" void kernel_launch(void* const* d_in, const int* in_sizes, int n_in,
                              void* d_out, int out_size, void* d_ws, size_t ws_size,
                              hipStream_t stream)
{
    const float* vf  = (const float*)d_in[0];
    const float* tf  = (const float*)d_in[1];
    const int*   ids = (const int*)d_in[2];

    float* ws_f = (float*)d_ws;
    float* scal = ws_f;                 // [0]=total [1]=S_mf [2]=trace [6]=bar
    float* rs   = ws_f + 16;            // 4096  (cs contiguous after rs)
    float* cs   = ws_f + 16 + 4096;     // 4096
    float* cntf = ws_f + 16 + 8192;     // 4096
    int* npart  = (int*)(ws_f + 16 + 12288);   // 256 partial num_pos counts
    uint* bar   = (uint*)(scal + 6);
    unsigned char* vhat8 = (unsigned char*)d_ws + 131072;   // 4096*768 fp8 = 3 MB
    unsigned char* that8 = vhat8 + (size_t)NB * DD;

    init_kernel<<<1, 64, 0, stream>>>(scal);
    fused_kernel<<<NBLK, 512, 0, stream>>>(vf, tf, ids, vhat8, that8,
                                           scal, rs, cs, cntf, npart, bar, (float*)d_out);
}

// Round 14
// 83.949 us; speedup vs baseline: 1.4355x; 1.0136x over previous
//
#include <hip/hip_runtime.h>
#include <hip/hip_bf16.h>

#define NB 4096
#define DD 768
#define NKT 12            // K-tiles of BK=64 (fp8): 768/64
#define NBLK 256          // grid: 256 blocks = 1 per CU (128KB LDS) -> all co-resident

typedef float f32x4 __attribute__((ext_vector_type(4)));
typedef long i64x2 __attribute__((ext_vector_type(2)));
typedef unsigned int uint;

#define WAITVM(N) asm volatile("s_waitcnt vmcnt(" #N ")" ::: "memory")

// ---------------- init: zero stats + grid-barrier counter (d_ws is poisoned 0xAA) ----------------
__global__ void init_kernel(float* scal)
{
    if (threadIdx.x < 16) scal[threadIdx.x] = 0.0f;
}

// ---------------- grid barrier: relaxed poll + one acquire on exit (low line pressure) ----------------
__device__ __forceinline__ void grid_bar(uint* bar, uint target, int t)
{
    __syncthreads();
    if (t == 0) {
        __hip_atomic_fetch_add(bar, 1u, __ATOMIC_ACQ_REL, __HIP_MEMORY_SCOPE_AGENT);
        while (__hip_atomic_load(bar, __ATOMIC_RELAXED, __HIP_MEMORY_SCOPE_AGENT) < target)
            __builtin_amdgcn_s_sleep(8);
        (void)__hip_atomic_load(bar, __ATOMIC_ACQUIRE, __HIP_MEMORY_SCOPE_AGENT);
    }
    __syncthreads();
}

// ---------------- staging: one K-tile unit = A[256][64B] + B[256][64B] fp8 (32 KB), ring-4 ----------------
// Rows are 64 B (4 chunks of 16 B): logical chunk c of row r at phys chunk c ^ ((r>>1)&3);
// linear LDS dest, pre-swizzled global source chunk (rule #21). Measured 0 bank conflicts.
__device__ __forceinline__ void stage_range(
    unsigned char* ldsAll,
    const unsigned char* __restrict__ vhat8, const unsigned char* __restrict__ that8,
    int rowBase, int colBase, int T, int i0, int i1, int wid, int lane)
{
    int u = T & 3;
    const unsigned char* src = (wid >= 4) ? that8 : vhat8;
    int tb = (wid >= 4) ? colBase : rowBase;
    int w4 = wid & 3;
    int logc = (lane & 3) ^ ((lane >> 3) & 3);
    int rowIn = w4 * 64 + (lane >> 2);
    unsigned char* dbase = ldsAll + u * 32768 + ((wid >= 4) ? 16384 : 0) + w4 * 4096;
    #pragma unroll
    for (int i = i0; i <= i1; ++i) {
        const unsigned char* g = src + (size_t)(tb + rowIn + i * 16) * DD + T * 64 + logc * 16;
        __builtin_amdgcn_global_load_lds(
            (const __attribute__((address_space(1))) void*)g,
            (__attribute__((address_space(3))) void*)(dbase + i * 1024),
            16, 0, 0);
    }
}

// ---------------- fully fused: normalize->fp8 + cnt | bar1 | GEMM+stats | bar2 | exp sums | bar3 | loss ----------------
__global__ __launch_bounds__(512, 2) void fused_kernel(
    const float* __restrict__ vf, const float* __restrict__ tf, const int* __restrict__ ids,
    unsigned char* __restrict__ vhat8, unsigned char* __restrict__ that8,
    float* scal, float* rs, float* cs, float* cntf, int* npart, uint* bar,
    float* __restrict__ out)
{
    __shared__ unsigned char ldsAll[4 * 32768];   // 128 KB ring; reused as ids stage in phase 0
    __shared__ int idr[256], idc[256];
    __shared__ float red[24];
    __shared__ float rs_l[256], cs_l[256];
    __shared__ int bp[16], wred_i[8];
    __shared__ float ra[8], rn[8];
    __shared__ float invT_sh, mf_sh;

    int rawb = blockIdx.x;
    int t = threadIdx.x, wid = t >> 6, lane = t & 63;

    // ===== phase 0a: normalize 32 rows/block -> fp8 e4m3, IDENTITY k-layout (coalesced writes) =====
    // Any k-bijection applied identically to A and B is dot-product-exact; identity makes
    // thread (c,lane)'s packed word land at word index c*64+lane — fully coalesced.
    {
        f32x4 xr[4][3];
        uint* dsts[4];
        #pragma unroll
        for (int it = 0; it < 4; ++it) {
            int row = rawb * 32 + wid * 4 + it;
            const float* src;
            if (row < NB) { src = vf + (size_t)row * DD; dsts[it] = (uint*)(vhat8 + (size_t)row * DD); }
            else          { src = tf + (size_t)(row - NB) * DD; dsts[it] = (uint*)(that8 + (size_t)(row - NB) * DD); }
            xr[it][0] = __builtin_nontemporal_load((const f32x4*)(src + lane * 4));
            xr[it][1] = __builtin_nontemporal_load((const f32x4*)(src + 256 + lane * 4));
            xr[it][2] = __builtin_nontemporal_load((const f32x4*)(src + 512 + lane * 4));
        }
        int idreg[8];
        #pragma unroll
        for (int i = 0; i < 8; ++i) idreg[i] = ids[t + i * 512];

        #pragma unroll
        for (int it = 0; it < 4; ++it) {
            float s = 0.f;
            #pragma unroll
            for (int c = 0; c < 3; ++c)
                s += xr[it][c][0]*xr[it][c][0] + xr[it][c][1]*xr[it][c][1]
                   + xr[it][c][2]*xr[it][c][2] + xr[it][c][3]*xr[it][c][3];
            #pragma unroll
            for (int off = 1; off < 64; off <<= 1) s += __shfl_xor(s, off, 64);
            float scale = 1.0f / sqrtf(s);
            #pragma unroll
            for (int c = 0; c < 3; ++c) {
                int p = __builtin_amdgcn_cvt_pk_fp8_f32(xr[it][c][0] * scale, xr[it][c][1] * scale, 0, false);
                p = __builtin_amdgcn_cvt_pk_fp8_f32(xr[it][c][2] * scale, xr[it][c][3] * scale, p, true);
                dsts[it][c * 64 + lane] = (uint)p;
            }
        }
        int* idsh = (int*)ldsAll;
        #pragma unroll
        for (int i = 0; i < 8; ++i) idsh[t + i * 512] = idreg[i];
    }
    __syncthreads();

    // ===== phase 0b: cnt — 32 lanes per id, int4 LDS scan =====
    {
        int* idsh = (int*)ldsAll;
        int sub = t >> 5, l32 = t & 31;
        int my = idsh[rawb * 16 + sub];
        const int4* idsh4 = (const int4*)idsh;
        int c = 0;
        #pragma unroll 8
        for (int j = l32; j < NB / 4; j += 32) {
            int4 v = idsh4[j];
            c += (v.x == my) + (v.y == my) + (v.z == my) + (v.w == my);
        }
        #pragma unroll
        for (int off = 16; off > 0; off >>= 1) c += __shfl_down(c, off, 32);
        if (l32 == 0) { cntf[rawb * 16 + sub] = (float)c; bp[sub] = c; }
    }
    // ===== phase 0c: zero rs+cs (contiguous 8192 floats starting at rs) =====
    if (t < 32) rs[rawb * 32 + t] = 0.0f;
    __syncthreads();
    if (t == 0) {
        int s = 0;
        #pragma unroll
        for (int i = 0; i < 16; ++i) s += bp[i];
        npart[rawb] = s;
    }

    // ===== grid barrier #1: vhat8/that8/cntf/npart/rs-zero published =====
    grid_bar(bar, NBLK, t);

    // ===== GEMM: 256x256 tile, 8 waves, fp8 BK=64, ring-4, 2-phase =====
    int rg = rawb & 7, sq = rawb >> 3;
    int by = (rg >> 1) * 4 + (sq >> 3);
    int bx = (rg & 1) * 8 + (sq & 7);
    int rowBase = by * 256, colBase = bx * 256;
    int wr = wid >> 2, wc = wid & 3;
    int fr = lane & 15, g = lane >> 4;

    f32x4 acc[8][4];
    #pragma unroll
    for (int m = 0; m < 8; ++m)
        #pragma unroll
        for (int n = 0; n < 4; ++n) acc[m][n] = (f32x4){0.f, 0.f, 0.f, 0.f};

    int pcoff = (g ^ ((fr >> 1) & 3)) * 16;
    int aoffB = (wr * 128 + fr) * 64 + pcoff;
    int boffB = 16384 + (wc * 64 + fr) * 64 + pcoff;

    stage_range(ldsAll, vhat8, that8, rowBase, colBase, 0, 0, 3, wid, lane);
    stage_range(ldsAll, vhat8, that8, rowBase, colBase, 1, 0, 3, wid, lane);
    stage_range(ldsAll, vhat8, that8, rowBase, colBase, 2, 0, 3, wid, lane);
    WAITVM(8);
    __builtin_amdgcn_s_barrier();

    for (int T = 0; T < NKT; ++T) {
        const unsigned char* U = ldsAll + (T & 3) * 32768;
        // phase A: reads(a0,bb) || stage half1(T+3) -> BAR -> MFMA m0..3 (x2 k-halves)
        i64x2 a0[4], bb[4];
        #pragma unroll
        for (int m = 0; m < 4; ++m) a0[m] = *(const i64x2*)(U + aoffB + m * 1024);
        #pragma unroll
        for (int n = 0; n < 4; ++n) bb[n] = *(const i64x2*)(U + boffB + n * 1024);
        if (T + 3 < NKT)
            stage_range(ldsAll, vhat8, that8, rowBase, colBase, T + 3, 0, 1, wid, lane);
        __builtin_amdgcn_s_barrier();
        __builtin_amdgcn_s_setprio(1);
        #pragma unroll
        for (int m = 0; m < 4; ++m)
            #pragma unroll
            for (int n = 0; n < 4; ++n) {
                acc[m][n] = __builtin_amdgcn_mfma_f32_16x16x32_fp8_fp8(a0[m][0], bb[n][0], acc[m][n], 0, 0, 0);
                acc[m][n] = __builtin_amdgcn_mfma_f32_16x16x32_fp8_fp8(a0[m][1], bb[n][1], acc[m][n], 0, 0, 0);
            }
        __builtin_amdgcn_s_setprio(0);
        __builtin_amdgcn_s_barrier();
        // phase B: reads(a1) || stage half2(T+3) -> BAR -> MFMA m4..7
        i64x2 a1[4];
        #pragma unroll
        for (int m = 0; m < 4; ++m) a1[m] = *(const i64x2*)(U + aoffB + (m + 4) * 1024);
        if (T + 3 < NKT)
            stage_range(ldsAll, vhat8, that8, rowBase, colBase, T + 3, 2, 3, wid, lane);
        __builtin_amdgcn_s_barrier();
        __builtin_amdgcn_s_setprio(1);
        #pragma unroll
        for (int m = 0; m < 4; ++m)
            #pragma unroll
            for (int n = 0; n < 4; ++n) {
                acc[m + 4][n] = __builtin_amdgcn_mfma_f32_16x16x32_fp8_fp8(a1[m][0], bb[n][0], acc[m + 4][n], 0, 0, 0);
                acc[m + 4][n] = __builtin_amdgcn_mfma_f32_16x16x32_fp8_fp8(a1[m][1], bb[n][1], acc[m + 4][n], 0, 0, 0);
            }
        __builtin_amdgcn_s_setprio(0);
        // tile boundary: T+1 staged; keep T+2/T+3 in flight (never vmcnt 0 mid-loop)
        if (T < NKT - 3)       { WAITVM(8); }
        else if (T == NKT - 3) { WAITVM(4); }
        else if (T == NKT - 2) { WAITVM(0); }
        __builtin_amdgcn_s_barrier();
    }

    // ===== stats: {total, S_mf, trace};  C/D: col=fr, row=g*4+reg [m89-verified, dtype-independent] =====
    if (t < 256) idr[t] = ids[rowBase + t];
    else         idc[t - 256] = ids[colBase + (t - 256)];
    __syncthreads();
    {
        float tsum = 0.f, msum = 0.f, dsum = 0.f;
        #pragma unroll
        for (int m = 0; m < 8; ++m) {
            int rl = wr * 128 + m * 16 + g * 4;
            #pragma unroll
            for (int n = 0; n < 4; ++n) {
                int cl = wc * 64 + n * 16 + fr;
                int colId = idc[cl];
                int gj = colBase + cl;
                #pragma unroll
                for (int r = 0; r < 4; ++r) {
                    float val = acc[m][n][r];
                    tsum += val;
                    if (idr[rl + r] == colId) msum += val;
                    if (rowBase + rl + r == gj) dsum += val;
                }
            }
        }
        #pragma unroll
        for (int off = 32; off > 0; off >>= 1) {
            tsum += __shfl_down(tsum, off, 64);
            msum += __shfl_down(msum, off, 64);
            dsum += __shfl_down(dsum, off, 64);
        }
        if (lane == 0) { red[wid] = tsum; red[8 + wid] = msum; red[16 + wid] = dsum; }
        __syncthreads();
        if (t == 0) {
            float s0 = 0.f, s1 = 0.f, s2 = 0.f;
            #pragma unroll
            for (int w = 0; w < 8; ++w) { s0 += red[w]; s1 += red[8 + w]; s2 += red[16 + w]; }
            atomicAdd(&scal[0], s0);
            atomicAdd(&scal[1], s1);
            atomicAdd(&scal[2], s2);
        }
    }

    // ===== np pre-reduce (npart published at bar1; off the post-bar2 critical path) =====
    {
        int myn = (t < NBLK) ? npart[t] : 0;
        #pragma unroll
        for (int off = 32; off > 0; off >>= 1) myn += __shfl_down(myn, off, 64);
        if (lane == 0) wred_i[wid] = myn;
    }
    if (t < 256) { rs_l[t] = 0.0f; cs_l[t] = 0.0f; }

    // ===== grid barrier #2: stats complete =====
    grid_bar(bar, 2 * NBLK, t);

    // ===== invT (t0 only; np already reduced) =====
    if (t == 0) {
        int npi = 0;
        #pragma unroll
        for (int w = 0; w < 8; ++w) npi += wred_i[w];
        float total = __hip_atomic_load(&scal[0], __ATOMIC_RELAXED, __HIP_MEMORY_SCOPE_AGENT);
        float mf    = __hip_atomic_load(&scal[1], __ATOMIC_RELAXED, __HIP_MEMORY_SCOPE_AGENT);
        float trace = __hip_atomic_load(&scal[2], __ATOMIC_RELAXED, __HIP_MEMORY_SCOPE_AGENT);
        float np = (float)npi;
        float pos_cnt = np - (float)NB;
        float neg_cnt = (float)NB * (float)NB - np;
        float pos_mean = (mf - trace) / fmaxf(1.0f, pos_cnt);
        float neg_mean = (total - mf) / fmaxf(1.0f, neg_cnt);
        float sep = pos_mean - neg_mean;
        float temp = 0.07f * (0.8f + 0.4f * expf(-2.0f * sep));
        temp = fminf(fmaxf(temp, 0.04f), 0.2f);
        invT_sh = 1.0f / temp;
        mf_sh = mf;
    }
    __syncthreads();
    float invT = invT_sh;

    // ===== exp((sim-1)/temp) row & col sums straight from registers =====
    #pragma unroll
    for (int m = 0; m < 8; ++m)
        #pragma unroll
        for (int n = 0; n < 4; ++n)
            #pragma unroll
            for (int r = 0; r < 4; ++r)
                acc[m][n][r] = __expf((acc[m][n][r] - 1.0f) * invT);
    #pragma unroll
    for (int m = 0; m < 8; ++m) {
        #pragma unroll
        for (int r = 0; r < 4; ++r) {
            float rp = 0.f;
            #pragma unroll
            for (int n = 0; n < 4; ++n) rp += acc[m][n][r];
            rp += __shfl_xor(rp, 1, 64);
            rp += __shfl_xor(rp, 2, 64);
            rp += __shfl_xor(rp, 4, 64);
            rp += __shfl_xor(rp, 8, 64);
            if (fr == 0) atomicAdd(&rs_l[wr * 128 + m * 16 + g * 4 + r], rp);
        }
    }
    #pragma unroll
    for (int n = 0; n < 4; ++n) {
        float cp = 0.f;
        #pragma unroll
        for (int m = 0; m < 8; ++m)
            #pragma unroll
            for (int r = 0; r < 4; ++r) cp += acc[m][n][r];
        cp += __shfl_xor(cp, 16, 64);
        cp += __shfl_xor(cp, 32, 64);
        if (g == 0) atomicAdd(&cs_l[wc * 64 + n * 16 + fr], cp);
    }
    __syncthreads();
    if (t < 256) {
        atomicAdd(&rs[rowBase + t], rs_l[t]);
        atomicAdd(&cs[colBase + t], cs_l[t]);
    }

    // ===== barrier #3: all arrive; only block 0 spins and finishes =====
    __syncthreads();
    if (t == 0)
        __hip_atomic_fetch_add(bar, 1u, __ATOMIC_ACQ_REL, __HIP_MEMORY_SCOPE_AGENT);
    if (rawb != 0) return;
    if (t == 0) {
        while (__hip_atomic_load(bar, __ATOMIC_RELAXED, __HIP_MEMORY_SCOPE_AGENT) < 3 * NBLK)
            __builtin_amdgcn_s_sleep(8);
        (void)__hip_atomic_load(bar, __ATOMIC_ACQUIRE, __HIP_MEMORY_SCOPE_AGENT);
    }
    __syncthreads();

    // ===== final loss (block 0, 512 threads) =====
    {
        float a = 0.f, npl = 0.f;
        for (int i = t; i < NB; i += 512) {
            float cf = cntf[i];
            a += cf * (logf(rs[i]) + logf(cs[i]));
            npl += cf;
        }
        #pragma unroll
        for (int off = 32; off > 0; off >>= 1) {
            a += __shfl_down(a, off, 64);
            npl += __shfl_down(npl, off, 64);
        }
        if (lane == 0) { ra[wid] = a; rn[wid] = npl; }
        __syncthreads();
        if (t == 0) {
            float A = 0.f, np = 0.f;
            #pragma unroll
            for (int w = 0; w < 8; ++w) { A += ra[w]; np += rn[w]; }
            // lse_row[i] = 1/temp + log(rs[i]); v2t+t2v = sum cnt*(lse_r+lse_c) - 2*mf/temp
            out[0] = (A + 2.0f * invT_sh * (np - mf_sh)) / (2.0f * np);
        }
    }
}

extern "C" void kernel_launch(void* const* d_in, const int* in_sizes, int n_in,
                              void* d_out, int out_size, void* d_ws, size_t ws_size,
                              hipStream_t stream)
{
    const float* vf  = (const float*)d_in[0];
    const float* tf  = (const float*)d_in[1];
    const int*   ids = (const int*)d_in[2];

    float* ws_f = (float*)d_ws;
    float* scal = ws_f;                 // [0]=total [1]=S_mf [2]=trace [6]=bar
    float* rs   = ws_f + 16;            // 4096  (cs contiguous after rs)
    float* cs   = ws_f + 16 + 4096;     // 4096
    float* cntf = ws_f + 16 + 8192;     // 4096
    int* npart  = (int*)(ws_f + 16 + 12288);   // 256 partial num_pos counts
    uint* bar   = (uint*)(scal + 6);
    unsigned char* vhat8 = (unsigned char*)d_ws + 131072;   // 4096*768 fp8 = 3 MB
    unsigned char* that8 = vhat8 + (size_t)NB * DD;

    init_kernel<<<1, 64, 0, stream>>>(scal);
    fused_kernel<<<NBLK, 512, 0, stream>>>(vf, tf, ids, vhat8, that8,
                                           scal, rs, cs, cntf, npart, bar, (float*)d_out);
}

// Round 15
// 78.399 us; speedup vs baseline: 1.5371x; 1.0708x over previous
//
#include <hip/hip_runtime.h>
#include <hip/hip_bf16.h>

#define NB 4096
#define DD 768
#define NKT 12            // K-tiles of BK=64 (fp8): 768/64
#define NBLK 256          // grid: 256 blocks = 1 per CU (128KB LDS) -> all co-resident

typedef float f32x4 __attribute__((ext_vector_type(4)));
typedef long i64x2 __attribute__((ext_vector_type(2)));
typedef unsigned int uint;

#define WAITVM(N) asm volatile("s_waitcnt vmcnt(" #N ")" ::: "memory")

// ---------------- init: zero stats + barrier tree (d_ws is poisoned 0xAA) ----------------
__global__ void init_kernel(float* scal, uint* bars)
{
    if (threadIdx.x < 16) scal[threadIdx.x] = 0.0f;
    bars[threadIdx.x] = 0u;     // 512 words: group counters (g*16), root (384), release (448)
}

// ---------------- two-level grid barrier: 16 group lines -> root -> release epoch ----------------
// Arrival: 16 serialized RMWs per line (parallel across 16 lines) + 16 root RMWs.
// Release: one word, read-only polled. Phase-coherent: block can't reach phase p+1
// before release>=p. Release-sequence via RMW chain preserves acq/rel transitivity.
__device__ __forceinline__ void grid_bar(uint* bars, uint phase, int rawb, int t)
{
    __syncthreads();
    if (t == 0) {
        int g = rawb & 15;
        uint prev = __hip_atomic_fetch_add(&bars[g * 16], 1u, __ATOMIC_ACQ_REL, __HIP_MEMORY_SCOPE_AGENT);
        if (prev == phase * 16u - 1u) {
            uint r = __hip_atomic_fetch_add(&bars[384], 1u, __ATOMIC_ACQ_REL, __HIP_MEMORY_SCOPE_AGENT);
            if (r == phase * 16u - 1u)
                __hip_atomic_store(&bars[448], phase, __ATOMIC_RELEASE, __HIP_MEMORY_SCOPE_AGENT);
        }
        while (__hip_atomic_load(&bars[448], __ATOMIC_RELAXED, __HIP_MEMORY_SCOPE_AGENT) < phase)
            __builtin_amdgcn_s_sleep(8);
        (void)__hip_atomic_load(&bars[448], __ATOMIC_ACQUIRE, __HIP_MEMORY_SCOPE_AGENT);
    }
    __syncthreads();
}

// ---------------- staging: one K-tile unit = A[256][64B] + B[256][64B] fp8 (32 KB), ring-4 ----------------
// Rows are 64 B (4 chunks of 16 B): logical chunk c of row r at phys chunk c ^ ((r>>1)&3);
// linear LDS dest, pre-swizzled global source chunk (rule #21). Measured 0 bank conflicts.
__device__ __forceinline__ void stage_range(
    unsigned char* ldsAll,
    const unsigned char* __restrict__ vhat8, const unsigned char* __restrict__ that8,
    int rowBase, int colBase, int T, int i0, int i1, int wid, int lane)
{
    int u = T & 3;
    const unsigned char* src = (wid >= 4) ? that8 : vhat8;
    int tb = (wid >= 4) ? colBase : rowBase;
    int w4 = wid & 3;
    int logc = (lane & 3) ^ ((lane >> 3) & 3);
    int rowIn = w4 * 64 + (lane >> 2);
    unsigned char* dbase = ldsAll + u * 32768 + ((wid >= 4) ? 16384 : 0) + w4 * 4096;
    #pragma unroll
    for (int i = i0; i <= i1; ++i) {
        const unsigned char* g = src + (size_t)(tb + rowIn + i * 16) * DD + T * 64 + logc * 16;
        __builtin_amdgcn_global_load_lds(
            (const __attribute__((address_space(1))) void*)g,
            (__attribute__((address_space(3))) void*)(dbase + i * 1024),
            16, 0, 0);
    }
}

// ---------------- fully fused: normalize->fp8 + cnt | bar1 | GEMM+stats | bar2 | exp sums | bar3 | loss ----------------
__global__ __launch_bounds__(512, 2) void fused_kernel(
    const float* __restrict__ vf, const float* __restrict__ tf, const int* __restrict__ ids,
    unsigned char* __restrict__ vhat8, unsigned char* __restrict__ that8,
    float* scal, float* rs, float* cs, float* cntf, int* npart, uint* bars,
    float* __restrict__ out)
{
    __shared__ unsigned char ldsAll[4 * 32768];   // 128 KB ring; reused as ids stage in phase 0
    __shared__ int idr[256], idc[256];
    __shared__ float red[24];
    __shared__ float rs_l[256], cs_l[256];
    __shared__ int bp[16], wred_i[8];
    __shared__ float ra[8], rn[8];
    __shared__ float invT_sh, mf_sh;

    int rawb = blockIdx.x;
    int t = threadIdx.x, wid = t >> 6, lane = t & 63;

    // ===== phase 0a: normalize 32 rows/block -> fp8 e4m3, identity k-layout (coalesced writes) =====
    {
        f32x4 xr[4][3];
        uint* dsts[4];
        #pragma unroll
        for (int it = 0; it < 4; ++it) {
            int row = rawb * 32 + wid * 4 + it;
            const float* src;
            if (row < NB) { src = vf + (size_t)row * DD; dsts[it] = (uint*)(vhat8 + (size_t)row * DD); }
            else          { src = tf + (size_t)(row - NB) * DD; dsts[it] = (uint*)(that8 + (size_t)(row - NB) * DD); }
            xr[it][0] = __builtin_nontemporal_load((const f32x4*)(src + lane * 4));
            xr[it][1] = __builtin_nontemporal_load((const f32x4*)(src + 256 + lane * 4));
            xr[it][2] = __builtin_nontemporal_load((const f32x4*)(src + 512 + lane * 4));
        }
        int idreg[8];
        #pragma unroll
        for (int i = 0; i < 8; ++i) idreg[i] = ids[t + i * 512];

        #pragma unroll
        for (int it = 0; it < 4; ++it) {
            float s = 0.f;
            #pragma unroll
            for (int c = 0; c < 3; ++c)
                s += xr[it][c][0]*xr[it][c][0] + xr[it][c][1]*xr[it][c][1]
                   + xr[it][c][2]*xr[it][c][2] + xr[it][c][3]*xr[it][c][3];
            #pragma unroll
            for (int off = 1; off < 64; off <<= 1) s += __shfl_xor(s, off, 64);
            float scale = 1.0f / sqrtf(s);
            #pragma unroll
            for (int c = 0; c < 3; ++c) {
                int p = __builtin_amdgcn_cvt_pk_fp8_f32(xr[it][c][0] * scale, xr[it][c][1] * scale, 0, false);
                p = __builtin_amdgcn_cvt_pk_fp8_f32(xr[it][c][2] * scale, xr[it][c][3] * scale, p, true);
                dsts[it][c * 64 + lane] = (uint)p;
            }
        }
        int* idsh = (int*)ldsAll;
        #pragma unroll
        for (int i = 0; i < 8; ++i) idsh[t + i * 512] = idreg[i];
    }
    __syncthreads();

    // ===== phase 0b: cnt — 32 lanes per id, int4 LDS scan =====
    {
        int* idsh = (int*)ldsAll;
        int sub = t >> 5, l32 = t & 31;
        int my = idsh[rawb * 16 + sub];
        const int4* idsh4 = (const int4*)idsh;
        int c = 0;
        #pragma unroll 8
        for (int j = l32; j < NB / 4; j += 32) {
            int4 v = idsh4[j];
            c += (v.x == my) + (v.y == my) + (v.z == my) + (v.w == my);
        }
        #pragma unroll
        for (int off = 16; off > 0; off >>= 1) c += __shfl_down(c, off, 32);
        if (l32 == 0) { cntf[rawb * 16 + sub] = (float)c; bp[sub] = c; }
    }
    // ===== phase 0c: zero rs+cs (contiguous 8192 floats starting at rs) =====
    if (t < 32) rs[rawb * 32 + t] = 0.0f;
    __syncthreads();
    if (t == 0) {
        int s = 0;
        #pragma unroll
        for (int i = 0; i < 16; ++i) s += bp[i];
        npart[rawb] = s;
    }

    // ===== grid barrier #1 =====
    grid_bar(bars, 1u, rawb, t);

    // ===== GEMM: 256x256 tile, 8 waves, fp8 BK=64, ring-4, 2-phase =====
    int rg = rawb & 7, sq = rawb >> 3;
    int by = (rg >> 1) * 4 + (sq >> 3);
    int bx = (rg & 1) * 8 + (sq & 7);
    int rowBase = by * 256, colBase = bx * 256;
    int wr = wid >> 2, wc = wid & 3;
    int fr = lane & 15, g = lane >> 4;

    f32x4 acc[8][4];
    #pragma unroll
    for (int m = 0; m < 8; ++m)
        #pragma unroll
        for (int n = 0; n < 4; ++n) acc[m][n] = (f32x4){0.f, 0.f, 0.f, 0.f};

    int pcoff = (g ^ ((fr >> 1) & 3)) * 16;
    int aoffB = (wr * 128 + fr) * 64 + pcoff;
    int boffB = 16384 + (wc * 64 + fr) * 64 + pcoff;

    stage_range(ldsAll, vhat8, that8, rowBase, colBase, 0, 0, 3, wid, lane);
    stage_range(ldsAll, vhat8, that8, rowBase, colBase, 1, 0, 3, wid, lane);
    stage_range(ldsAll, vhat8, that8, rowBase, colBase, 2, 0, 3, wid, lane);
    WAITVM(8);
    __builtin_amdgcn_s_barrier();

    for (int T = 0; T < NKT; ++T) {
        const unsigned char* U = ldsAll + (T & 3) * 32768;
        // phase A: reads(a0,bb) || stage half1(T+3) -> BAR -> MFMA m0..3 (x2 k-halves)
        i64x2 a0[4], bb[4];
        #pragma unroll
        for (int m = 0; m < 4; ++m) a0[m] = *(const i64x2*)(U + aoffB + m * 1024);
        #pragma unroll
        for (int n = 0; n < 4; ++n) bb[n] = *(const i64x2*)(U + boffB + n * 1024);
        if (T + 3 < NKT)
            stage_range(ldsAll, vhat8, that8, rowBase, colBase, T + 3, 0, 1, wid, lane);
        __builtin_amdgcn_s_barrier();
        __builtin_amdgcn_s_setprio(1);
        #pragma unroll
        for (int m = 0; m < 4; ++m)
            #pragma unroll
            for (int n = 0; n < 4; ++n) {
                acc[m][n] = __builtin_amdgcn_mfma_f32_16x16x32_fp8_fp8(a0[m][0], bb[n][0], acc[m][n], 0, 0, 0);
                acc[m][n] = __builtin_amdgcn_mfma_f32_16x16x32_fp8_fp8(a0[m][1], bb[n][1], acc[m][n], 0, 0, 0);
            }
        __builtin_amdgcn_s_setprio(0);
        __builtin_amdgcn_s_barrier();
        // phase B: reads(a1) || stage half2(T+3) -> BAR -> MFMA m4..7
        i64x2 a1[4];
        #pragma unroll
        for (int m = 0; m < 4; ++m) a1[m] = *(const i64x2*)(U + aoffB + (m + 4) * 1024);
        if (T + 3 < NKT)
            stage_range(ldsAll, vhat8, that8, rowBase, colBase, T + 3, 2, 3, wid, lane);
        __builtin_amdgcn_s_barrier();
        __builtin_amdgcn_s_setprio(1);
        #pragma unroll
        for (int m = 0; m < 4; ++m)
            #pragma unroll
            for (int n = 0; n < 4; ++n) {
                acc[m + 4][n] = __builtin_amdgcn_mfma_f32_16x16x32_fp8_fp8(a1[m][0], bb[n][0], acc[m + 4][n], 0, 0, 0);
                acc[m + 4][n] = __builtin_amdgcn_mfma_f32_16x16x32_fp8_fp8(a1[m][1], bb[n][1], acc[m + 4][n], 0, 0, 0);
            }
        __builtin_amdgcn_s_setprio(0);
        // tile boundary: T+1 staged; keep T+2/T+3 in flight (never vmcnt 0 mid-loop)
        if (T < NKT - 3)       { WAITVM(8); }
        else if (T == NKT - 3) { WAITVM(4); }
        else if (T == NKT - 2) { WAITVM(0); }
        __builtin_amdgcn_s_barrier();
    }

    // ===== stats: {total, S_mf, trace};  C/D: col=fr, row=g*4+reg [m89-verified, dtype-independent] =====
    if (t < 256) idr[t] = ids[rowBase + t];
    else         idc[t - 256] = ids[colBase + (t - 256)];
    __syncthreads();
    {
        float tsum = 0.f, msum = 0.f, dsum = 0.f;
        #pragma unroll
        for (int m = 0; m < 8; ++m) {
            int rl = wr * 128 + m * 16 + g * 4;
            #pragma unroll
            for (int n = 0; n < 4; ++n) {
                int cl = wc * 64 + n * 16 + fr;
                int colId = idc[cl];
                int gj = colBase + cl;
                #pragma unroll
                for (int r = 0; r < 4; ++r) {
                    float val = acc[m][n][r];
                    tsum += val;
                    if (idr[rl + r] == colId) msum += val;
                    if (rowBase + rl + r == gj) dsum += val;
                }
            }
        }
        #pragma unroll
        for (int off = 32; off > 0; off >>= 1) {
            tsum += __shfl_down(tsum, off, 64);
            msum += __shfl_down(msum, off, 64);
            dsum += __shfl_down(dsum, off, 64);
        }
        if (lane == 0) { red[wid] = tsum; red[8 + wid] = msum; red[16 + wid] = dsum; }
        __syncthreads();
        if (t == 0) {
            float s0 = 0.f, s1 = 0.f, s2 = 0.f;
            #pragma unroll
            for (int w = 0; w < 8; ++w) { s0 += red[w]; s1 += red[8 + w]; s2 += red[16 + w]; }
            atomicAdd(&scal[0], s0);
            atomicAdd(&scal[1], s1);
            atomicAdd(&scal[2], s2);
        }
    }

    // ===== np pre-reduce (npart published at bar1; off the post-bar2 critical path) =====
    {
        int myn = (t < NBLK) ? npart[t] : 0;
        #pragma unroll
        for (int off = 32; off > 0; off >>= 1) myn += __shfl_down(myn, off, 64);
        if (lane == 0) wred_i[wid] = myn;
    }
    if (t < 256) { rs_l[t] = 0.0f; cs_l[t] = 0.0f; }

    // ===== grid barrier #2: stats complete =====
    grid_bar(bars, 2u, rawb, t);

    // ===== invT (t0 only; np already reduced) =====
    if (t == 0) {
        int npi = 0;
        #pragma unroll
        for (int w = 0; w < 8; ++w) npi += wred_i[w];
        float total = __hip_atomic_load(&scal[0], __ATOMIC_RELAXED, __HIP_MEMORY_SCOPE_AGENT);
        float mf    = __hip_atomic_load(&scal[1], __ATOMIC_RELAXED, __HIP_MEMORY_SCOPE_AGENT);
        float trace = __hip_atomic_load(&scal[2], __ATOMIC_RELAXED, __HIP_MEMORY_SCOPE_AGENT);
        float np = (float)npi;
        float pos_cnt = np - (float)NB;
        float neg_cnt = (float)NB * (float)NB - np;
        float pos_mean = (mf - trace) / fmaxf(1.0f, pos_cnt);
        float neg_mean = (total - mf) / fmaxf(1.0f, neg_cnt);
        float sep = pos_mean - neg_mean;
        float temp = 0.07f * (0.8f + 0.4f * expf(-2.0f * sep));
        temp = fminf(fmaxf(temp, 0.04f), 0.2f);
        invT_sh = 1.0f / temp;
        mf_sh = mf;
    }
    __syncthreads();
    float invT = invT_sh;

    // ===== exp((sim-1)/temp) row & col sums straight from registers =====
    #pragma unroll
    for (int m = 0; m < 8; ++m)
        #pragma unroll
        for (int n = 0; n < 4; ++n)
            #pragma unroll
            for (int r = 0; r < 4; ++r)
                acc[m][n][r] = __expf((acc[m][n][r] - 1.0f) * invT);
    #pragma unroll
    for (int m = 0; m < 8; ++m) {
        #pragma unroll
        for (int r = 0; r < 4; ++r) {
            float rp = 0.f;
            #pragma unroll
            for (int n = 0; n < 4; ++n) rp += acc[m][n][r];
            rp += __shfl_xor(rp, 1, 64);
            rp += __shfl_xor(rp, 2, 64);
            rp += __shfl_xor(rp, 4, 64);
            rp += __shfl_xor(rp, 8, 64);
            if (fr == 0) atomicAdd(&rs_l[wr * 128 + m * 16 + g * 4 + r], rp);
        }
    }
    #pragma unroll
    for (int n = 0; n < 4; ++n) {
        float cp = 0.f;
        #pragma unroll
        for (int m = 0; m < 8; ++m)
            #pragma unroll
            for (int r = 0; r < 4; ++r) cp += acc[m][n][r];
        cp += __shfl_xor(cp, 16, 64);
        cp += __shfl_xor(cp, 32, 64);
        if (g == 0) atomicAdd(&cs_l[wc * 64 + n * 16 + fr], cp);
    }
    __syncthreads();
    if (t < 256) {
        atomicAdd(&rs[rowBase + t], rs_l[t]);
        atomicAdd(&cs[colBase + t], cs_l[t]);
    }

    // ===== grid barrier #3: rs/cs complete =====
    grid_bar(bars, 3u, rawb, t);
    if (rawb != 0) return;

    // ===== final loss (block 0, 512 threads) =====
    {
        float a = 0.f, npl = 0.f;
        for (int i = t; i < NB; i += 512) {
            float cf = cntf[i];
            a += cf * (logf(rs[i]) + logf(cs[i]));
            npl += cf;
        }
        #pragma unroll
        for (int off = 32; off > 0; off >>= 1) {
            a += __shfl_down(a, off, 64);
            npl += __shfl_down(npl, off, 64);
        }
        if (lane == 0) { ra[wid] = a; rn[wid] = npl; }
        __syncthreads();
        if (t == 0) {
            float A = 0.f, np = 0.f;
            #pragma unroll
            for (int w = 0; w < 8; ++w) { A += ra[w]; np += rn[w]; }
            // lse_row[i] = 1/temp + log(rs[i]); v2t+t2v = sum cnt*(lse_r+lse_c) - 2*mf/temp
            out[0] = (A + 2.0f * invT_sh * (np - mf_sh)) / (2.0f * np);
        }
    }
}

extern "C" void kernel_launch(void* const* d_in, const int* in_sizes, int n_in,
                              void* d_out, int out_size, void* d_ws, size_t ws_size,
                              hipStream_t stream)
{
    const float* vf  = (const float*)d_in[0];
    const float* tf  = (const float*)d_in[1];
    const int*   ids = (const int*)d_in[2];

    float* ws_f = (float*)d_ws;
    float* scal = ws_f;                 // [0]=total [1]=S_mf [2]=trace
    float* rs   = ws_f + 16;            // 4096  (cs contiguous after rs)
    float* cs   = ws_f + 16 + 4096;     // 4096
    float* cntf = ws_f + 16 + 8192;     // 4096
    int* npart  = (int*)(ws_f + 16 + 12288);   // 256 partial num_pos counts
    uint* bars  = (uint*)(ws_f + 16 + 12800);  // 512 words: tree barrier state
    unsigned char* vhat8 = (unsigned char*)d_ws + 131072;   // 4096*768 fp8 = 3 MB
    unsigned char* that8 = vhat8 + (size_t)NB * DD;

    init_kernel<<<1, 512, 0, stream>>>(scal, bars);
    fused_kernel<<<NBLK, 512, 0, stream>>>(vf, tf, ids, vhat8, that8,
                                           scal, rs, cs, cntf, npart, bars, (float*)d_out);
}

// Round 16
// 77.436 us; speedup vs baseline: 1.5563x; 1.0124x over previous
//
#include <hip/hip_runtime.h>
#include <hip/hip_bf16.h>

#define NB 4096
#define DD 768
#define NKT 12            // K-tiles of BK=64 (fp8): 768/64
#define NBLK 256          // grid: 256 blocks = 1 per CU (128KB LDS) -> all co-resident

typedef float f32x4 __attribute__((ext_vector_type(4)));
typedef long i64x2 __attribute__((ext_vector_type(2)));
typedef unsigned int uint;

#define WAITVM(N) asm volatile("s_waitcnt vmcnt(" #N ")" ::: "memory")

// ---------------- init: zero stats + barrier/flag state (d_ws is poisoned 0xAA) ----------------
// bars[0..383]: tree group counters (g*16); bars[384]: root; bars[448]: release epoch;
// bars[464]: final ticket; bars[512 + p*16] p=0..31: panel-ready flags (8 producers each).
__global__ void init_kernel(float* scal, uint* bars)
{
    int t = threadIdx.x;
    if (t < 16) scal[t] = 0.0f;
    bars[t] = 0u;
    bars[512 + t] = 0u;
}

// ---------------- tree grid barrier (phase-coherent; used once, phase=1) ----------------
__device__ __forceinline__ void grid_bar(uint* bars, uint phase, int rawb, int t)
{
    __syncthreads();
    if (t == 0) {
        int g = rawb & 15;
        uint prev = __hip_atomic_fetch_add(&bars[g * 16], 1u, __ATOMIC_ACQ_REL, __HIP_MEMORY_SCOPE_AGENT);
        if (prev == phase * 16u - 1u) {
            uint r = __hip_atomic_fetch_add(&bars[384], 1u, __ATOMIC_ACQ_REL, __HIP_MEMORY_SCOPE_AGENT);
            if (r == phase * 16u - 1u)
                __hip_atomic_store(&bars[448], phase, __ATOMIC_RELEASE, __HIP_MEMORY_SCOPE_AGENT);
        }
        while (__hip_atomic_load(&bars[448], __ATOMIC_RELAXED, __HIP_MEMORY_SCOPE_AGENT) < phase)
            __builtin_amdgcn_s_sleep(8);
        (void)__hip_atomic_load(&bars[448], __ATOMIC_ACQUIRE, __HIP_MEMORY_SCOPE_AGENT);
    }
    __syncthreads();
}

// ---------------- staging: one K-tile unit = A[256][64B] + B[256][64B] fp8 (32 KB), ring-4 ----------------
// Rows are 64 B (4 chunks of 16 B): logical chunk c of row r at phys chunk c ^ ((r>>1)&3);
// linear LDS dest, pre-swizzled global source chunk (rule #21). Measured 0 bank conflicts.
__device__ __forceinline__ void stage_range(
    unsigned char* ldsAll,
    const unsigned char* __restrict__ vhat8, const unsigned char* __restrict__ that8,
    int rowBase, int colBase, int T, int i0, int i1, int wid, int lane)
{
    int u = T & 3;
    const unsigned char* src = (wid >= 4) ? that8 : vhat8;
    int tb = (wid >= 4) ? colBase : rowBase;
    int w4 = wid & 3;
    int logc = (lane & 3) ^ ((lane >> 3) & 3);
    int rowIn = w4 * 64 + (lane >> 2);
    unsigned char* dbase = ldsAll + u * 32768 + ((wid >= 4) ? 16384 : 0) + w4 * 4096;
    #pragma unroll
    for (int i = i0; i <= i1; ++i) {
        const unsigned char* g = src + (size_t)(tb + rowIn + i * 16) * DD + T * 64 + logc * 16;
        __builtin_amdgcn_global_load_lds(
            (const __attribute__((address_space(1))) void*)g,
            (__attribute__((address_space(3))) void*)(dbase + i * 1024),
            16, 0, 0);
    }
}

// ---------------- fully fused: normalize->fp8 + cnt | panel-flags | GEMM+stats | tree-bar | exp | ticket | loss ----------------
__global__ __launch_bounds__(512, 2) void fused_kernel(
    const float* __restrict__ vf, const float* __restrict__ tf, const int* __restrict__ ids,
    unsigned char* __restrict__ vhat8, unsigned char* __restrict__ that8,
    float* scal, float* rs, float* cs, float* cntf, int* npart, uint* bars,
    float* __restrict__ out)
{
    __shared__ unsigned char ldsAll[4 * 32768];   // 128 KB ring; reused as ids stage in phase 0
    __shared__ int idr[256], idc[256];
    __shared__ float red[24];
    __shared__ float rs_l[256], cs_l[256];
    __shared__ int bp[16], wred_i[8];
    __shared__ float ra[8], rn[8];
    __shared__ float invT_sh, mf_sh;
    __shared__ uint tick_sh;

    int rawb = blockIdx.x;
    int t = threadIdx.x, wid = t >> 6, lane = t & 63;

    // ===== phase 0a: normalize 32 rows/block -> fp8 e4m3, identity k-layout (coalesced writes) =====
    {
        f32x4 xr[4][3];
        uint* dsts[4];
        #pragma unroll
        for (int it = 0; it < 4; ++it) {
            int row = rawb * 32 + wid * 4 + it;
            const float* src;
            if (row < NB) { src = vf + (size_t)row * DD; dsts[it] = (uint*)(vhat8 + (size_t)row * DD); }
            else          { src = tf + (size_t)(row - NB) * DD; dsts[it] = (uint*)(that8 + (size_t)(row - NB) * DD); }
            xr[it][0] = __builtin_nontemporal_load((const f32x4*)(src + lane * 4));
            xr[it][1] = __builtin_nontemporal_load((const f32x4*)(src + 256 + lane * 4));
            xr[it][2] = __builtin_nontemporal_load((const f32x4*)(src + 512 + lane * 4));
        }
        int idreg[8];
        #pragma unroll
        for (int i = 0; i < 8; ++i) idreg[i] = ids[t + i * 512];

        #pragma unroll
        for (int it = 0; it < 4; ++it) {
            float s = 0.f;
            #pragma unroll
            for (int c = 0; c < 3; ++c)
                s += xr[it][c][0]*xr[it][c][0] + xr[it][c][1]*xr[it][c][1]
                   + xr[it][c][2]*xr[it][c][2] + xr[it][c][3]*xr[it][c][3];
            #pragma unroll
            for (int off = 1; off < 64; off <<= 1) s += __shfl_xor(s, off, 64);
            float scale = 1.0f / sqrtf(s);
            #pragma unroll
            for (int c = 0; c < 3; ++c) {
                int p = __builtin_amdgcn_cvt_pk_fp8_f32(xr[it][c][0] * scale, xr[it][c][1] * scale, 0, false);
                p = __builtin_amdgcn_cvt_pk_fp8_f32(xr[it][c][2] * scale, xr[it][c][3] * scale, p, true);
                dsts[it][c * 64 + lane] = (uint)p;
            }
        }
        int* idsh = (int*)ldsAll;
        #pragma unroll
        for (int i = 0; i < 8; ++i) idsh[t + i * 512] = idreg[i];
    }
    __syncthreads();
    // panel-ready release: this block's 32 rows belong to combined panel rawb/8 (0..31)
    if (t == 0)
        __hip_atomic_fetch_add(&bars[512 + (rawb >> 3) * 16], 1u, __ATOMIC_ACQ_REL, __HIP_MEMORY_SCOPE_AGENT);

    // ===== phase 0b: cnt — 32 lanes per id, int4 LDS scan (runs while producers finish) =====
    {
        int* idsh = (int*)ldsAll;
        int sub = t >> 5, l32 = t & 31;
        int my = idsh[rawb * 16 + sub];
        const int4* idsh4 = (const int4*)idsh;
        int c = 0;
        #pragma unroll 8
        for (int j = l32; j < NB / 4; j += 32) {
            int4 v = idsh4[j];
            c += (v.x == my) + (v.y == my) + (v.z == my) + (v.w == my);
        }
        #pragma unroll
        for (int off = 16; off > 0; off >>= 1) c += __shfl_down(c, off, 32);
        if (l32 == 0) { cntf[rawb * 16 + sub] = (float)c; bp[sub] = c; }
    }
    // ===== phase 0c: zero rs+cs (contiguous 8192 floats starting at rs) =====
    if (t < 32) rs[rawb * 32 + t] = 0.0f;
    __syncthreads();
    if (t == 0) {
        int s = 0;
        #pragma unroll
        for (int i = 0; i < 16; ++i) s += bp[i];
        npart[rawb] = s;
    }

    // ===== GEMM geometry (needed for panel poll) =====
    int rg = rawb & 7, sq = rawb >> 3;
    int by = (rg >> 1) * 4 + (sq >> 3);
    int bx = (rg & 1) * 8 + (sq & 7);
    int rowBase = by * 256, colBase = bx * 256;
    int wr = wid >> 2, wc = wid & 3;
    int fr = lane & 15, g = lane >> 4;

    // ===== panel-ready poll: need vhat panel `by` and that panel `bx` (8 producers each) =====
    __syncthreads();
    if (t == 0) {
        uint* fA = &bars[512 + by * 16];
        uint* fB = &bars[512 + (16 + bx) * 16];
        while (__hip_atomic_load(fA, __ATOMIC_RELAXED, __HIP_MEMORY_SCOPE_AGENT) < 8u)
            __builtin_amdgcn_s_sleep(4);
        while (__hip_atomic_load(fB, __ATOMIC_RELAXED, __HIP_MEMORY_SCOPE_AGENT) < 8u)
            __builtin_amdgcn_s_sleep(4);
        (void)__hip_atomic_load(fA, __ATOMIC_ACQUIRE, __HIP_MEMORY_SCOPE_AGENT);
        (void)__hip_atomic_load(fB, __ATOMIC_ACQUIRE, __HIP_MEMORY_SCOPE_AGENT);
    }
    __syncthreads();

    // ===== GEMM: 256x256 tile, 8 waves, fp8 BK=64, ring-4, 2-phase =====
    f32x4 acc[8][4];
    #pragma unroll
    for (int m = 0; m < 8; ++m)
        #pragma unroll
        for (int n = 0; n < 4; ++n) acc[m][n] = (f32x4){0.f, 0.f, 0.f, 0.f};

    int pcoff = (g ^ ((fr >> 1) & 3)) * 16;
    int aoffB = (wr * 128 + fr) * 64 + pcoff;
    int boffB = 16384 + (wc * 64 + fr) * 64 + pcoff;

    stage_range(ldsAll, vhat8, that8, rowBase, colBase, 0, 0, 3, wid, lane);
    stage_range(ldsAll, vhat8, that8, rowBase, colBase, 1, 0, 3, wid, lane);
    stage_range(ldsAll, vhat8, that8, rowBase, colBase, 2, 0, 3, wid, lane);
    WAITVM(8);
    __builtin_amdgcn_s_barrier();

    for (int T = 0; T < NKT; ++T) {
        const unsigned char* U = ldsAll + (T & 3) * 32768;
        // phase A: reads(a0,bb) || stage half1(T+3) -> BAR -> MFMA m0..3 (x2 k-halves)
        i64x2 a0[4], bb[4];
        #pragma unroll
        for (int m = 0; m < 4; ++m) a0[m] = *(const i64x2*)(U + aoffB + m * 1024);
        #pragma unroll
        for (int n = 0; n < 4; ++n) bb[n] = *(const i64x2*)(U + boffB + n * 1024);
        if (T + 3 < NKT)
            stage_range(ldsAll, vhat8, that8, rowBase, colBase, T + 3, 0, 1, wid, lane);
        __builtin_amdgcn_s_barrier();
        __builtin_amdgcn_s_setprio(1);
        #pragma unroll
        for (int m = 0; m < 4; ++m)
            #pragma unroll
            for (int n = 0; n < 4; ++n) {
                acc[m][n] = __builtin_amdgcn_mfma_f32_16x16x32_fp8_fp8(a0[m][0], bb[n][0], acc[m][n], 0, 0, 0);
                acc[m][n] = __builtin_amdgcn_mfma_f32_16x16x32_fp8_fp8(a0[m][1], bb[n][1], acc[m][n], 0, 0, 0);
            }
        __builtin_amdgcn_s_setprio(0);
        __builtin_amdgcn_s_barrier();
        // phase B: reads(a1) || stage half2(T+3) -> BAR -> MFMA m4..7
        i64x2 a1[4];
        #pragma unroll
        for (int m = 0; m < 4; ++m) a1[m] = *(const i64x2*)(U + aoffB + (m + 4) * 1024);
        if (T + 3 < NKT)
            stage_range(ldsAll, vhat8, that8, rowBase, colBase, T + 3, 2, 3, wid, lane);
        __builtin_amdgcn_s_barrier();
        __builtin_amdgcn_s_setprio(1);
        #pragma unroll
        for (int m = 0; m < 4; ++m)
            #pragma unroll
            for (int n = 0; n < 4; ++n) {
                acc[m + 4][n] = __builtin_amdgcn_mfma_f32_16x16x32_fp8_fp8(a1[m][0], bb[n][0], acc[m + 4][n], 0, 0, 0);
                acc[m + 4][n] = __builtin_amdgcn_mfma_f32_16x16x32_fp8_fp8(a1[m][1], bb[n][1], acc[m + 4][n], 0, 0, 0);
            }
        __builtin_amdgcn_s_setprio(0);
        // tile boundary: T+1 staged; keep T+2/T+3 in flight (never vmcnt 0 mid-loop)
        if (T < NKT - 3)       { WAITVM(8); }
        else if (T == NKT - 3) { WAITVM(4); }
        else if (T == NKT - 2) { WAITVM(0); }
        __builtin_amdgcn_s_barrier();
    }

    // ===== stats: {total, S_mf, trace};  C/D: col=fr, row=g*4+reg [m89-verified, dtype-independent] =====
    if (t < 256) idr[t] = ids[rowBase + t];
    else         idc[t - 256] = ids[colBase + (t - 256)];
    __syncthreads();
    {
        float tsum = 0.f, msum = 0.f, dsum = 0.f;
        #pragma unroll
        for (int m = 0; m < 8; ++m) {
            int rl = wr * 128 + m * 16 + g * 4;
            #pragma unroll
            for (int n = 0; n < 4; ++n) {
                int cl = wc * 64 + n * 16 + fr;
                int colId = idc[cl];
                int gj = colBase + cl;
                #pragma unroll
                for (int r = 0; r < 4; ++r) {
                    float val = acc[m][n][r];
                    tsum += val;
                    if (idr[rl + r] == colId) msum += val;
                    if (rowBase + rl + r == gj) dsum += val;
                }
            }
        }
        #pragma unroll
        for (int off = 32; off > 0; off >>= 1) {
            tsum += __shfl_down(tsum, off, 64);
            msum += __shfl_down(msum, off, 64);
            dsum += __shfl_down(dsum, off, 64);
        }
        if (lane == 0) { red[wid] = tsum; red[8 + wid] = msum; red[16 + wid] = dsum; }
        __syncthreads();
        if (t == 0) {
            float s0 = 0.f, s1 = 0.f, s2 = 0.f;
            #pragma unroll
            for (int w = 0; w < 8; ++w) { s0 += red[w]; s1 += red[8 + w]; s2 += red[16 + w]; }
            atomicAdd(&scal[0], s0);
            atomicAdd(&scal[1], s1);
            atomicAdd(&scal[2], s2);
        }
    }

    // ===== np pre-reduce (off the post-barrier critical path) =====
    {
        int myn = (t < NBLK) ? npart[t] : 0;
        #pragma unroll
        for (int off = 32; off > 0; off >>= 1) myn += __shfl_down(myn, off, 64);
        if (lane == 0) wred_i[wid] = myn;
    }
    if (t < 256) { rs_l[t] = 0.0f; cs_l[t] = 0.0f; }

    // ===== tree grid barrier (phase 1): stats complete =====
    grid_bar(bars, 1u, rawb, t);

    // ===== invT (t0 only; np already reduced) =====
    if (t == 0) {
        int npi = 0;
        #pragma unroll
        for (int w = 0; w < 8; ++w) npi += wred_i[w];
        float total = __hip_atomic_load(&scal[0], __ATOMIC_RELAXED, __HIP_MEMORY_SCOPE_AGENT);
        float mf    = __hip_atomic_load(&scal[1], __ATOMIC_RELAXED, __HIP_MEMORY_SCOPE_AGENT);
        float trace = __hip_atomic_load(&scal[2], __ATOMIC_RELAXED, __HIP_MEMORY_SCOPE_AGENT);
        float np = (float)npi;
        float pos_cnt = np - (float)NB;
        float neg_cnt = (float)NB * (float)NB - np;
        float pos_mean = (mf - trace) / fmaxf(1.0f, pos_cnt);
        float neg_mean = (total - mf) / fmaxf(1.0f, neg_cnt);
        float sep = pos_mean - neg_mean;
        float temp = 0.07f * (0.8f + 0.4f * expf(-2.0f * sep));
        temp = fminf(fmaxf(temp, 0.04f), 0.2f);
        invT_sh = 1.0f / temp;
        mf_sh = mf;
    }
    __syncthreads();
    float invT = invT_sh;

    // ===== exp((sim-1)/temp) row & col sums straight from registers =====
    #pragma unroll
    for (int m = 0; m < 8; ++m)
        #pragma unroll
        for (int n = 0; n < 4; ++n)
            #pragma unroll
            for (int r = 0; r < 4; ++r)
                acc[m][n][r] = __expf((acc[m][n][r] - 1.0f) * invT);
    #pragma unroll
    for (int m = 0; m < 8; ++m) {
        #pragma unroll
        for (int r = 0; r < 4; ++r) {
            float rp = 0.f;
            #pragma unroll
            for (int n = 0; n < 4; ++n) rp += acc[m][n][r];
            rp += __shfl_xor(rp, 1, 64);
            rp += __shfl_xor(rp, 2, 64);
            rp += __shfl_xor(rp, 4, 64);
            rp += __shfl_xor(rp, 8, 64);
            if (fr == 0) atomicAdd(&rs_l[wr * 128 + m * 16 + g * 4 + r], rp);
        }
    }
    #pragma unroll
    for (int n = 0; n < 4; ++n) {
        float cp = 0.f;
        #pragma unroll
        for (int m = 0; m < 8; ++m)
            #pragma unroll
            for (int r = 0; r < 4; ++r) cp += acc[m][n][r];
        cp += __shfl_xor(cp, 16, 64);
        cp += __shfl_xor(cp, 32, 64);
        if (g == 0) atomicAdd(&cs_l[wc * 64 + n * 16 + fr], cp);
    }
    __syncthreads();
    if (t < 256) {
        atomicAdd(&rs[rowBase + t], rs_l[t]);
        atomicAdd(&cs[colBase + t], cs_l[t]);
    }

    // ===== last-block ticket: the 256th arriver runs the final loss; everyone else exits =====
    __syncthreads();
    if (t == 0) {
        uint prev = __hip_atomic_fetch_add(&bars[464], 1u, __ATOMIC_ACQ_REL, __HIP_MEMORY_SCOPE_AGENT);
        tick_sh = prev;
    }
    __syncthreads();
    if (tick_sh != NBLK - 1) return;

    // ===== final loss (last-arriving block; its ACQ_REL RMW synchronized with all others) =====
    {
        float a = 0.f, npl = 0.f;
        for (int i = t; i < NB; i += 512) {
            float cf = cntf[i];
            a += cf * (logf(rs[i]) + logf(cs[i]));
            npl += cf;
        }
        #pragma unroll
        for (int off = 32; off > 0; off >>= 1) {
            a += __shfl_down(a, off, 64);
            npl += __shfl_down(npl, off, 64);
        }
        if (lane == 0) { ra[wid] = a; rn[wid] = npl; }
        __syncthreads();
        if (t == 0) {
            float A = 0.f, np = 0.f;
            #pragma unroll
            for (int w = 0; w < 8; ++w) { A += ra[w]; np += rn[w]; }
            // lse_row[i] = 1/temp + log(rs[i]); v2t+t2v = sum cnt*(lse_r+lse_c) - 2*mf/temp
            out[0] = (A + 2.0f * invT_sh * (np - mf_sh)) / (2.0f * np);
        }
    }
}

extern "C" void kernel_launch(void* const* d_in, const int* in_sizes, int n_in,
                              void* d_out, int out_size, void* d_ws, size_t ws_size,
                              hipStream_t stream)
{
    const float* vf  = (const float*)d_in[0];
    const float* tf  = (const float*)d_in[1];
    const int*   ids = (const int*)d_in[2];

    float* ws_f = (float*)d_ws;
    float* scal = ws_f;                 // [0]=total [1]=S_mf [2]=trace
    float* rs   = ws_f + 16;            // 4096  (cs contiguous after rs)
    float* cs   = ws_f + 16 + 4096;     // 4096
    float* cntf = ws_f + 16 + 8192;     // 4096
    int* npart  = (int*)(ws_f + 16 + 12288);   // 256 partial num_pos counts
    uint* bars  = (uint*)(ws_f + 16 + 12800);  // 1024 words: tree barrier + ticket + panel flags
    unsigned char* vhat8 = (unsigned char*)d_ws + 131072;   // 4096*768 fp8 = 3 MB
    unsigned char* that8 = vhat8 + (size_t)NB * DD;

    init_kernel<<<1, 512, 0, stream>>>(scal, bars);
    fused_kernel<<<NBLK, 512, 0, stream>>>(vf, tf, ids, vhat8, that8,
                                           scal, rs, cs, cntf, npart, bars, (float*)d_out);
}

// Round 18
// 76.133 us; speedup vs baseline: 1.5829x; 1.0171x over previous
//
#include <hip/hip_runtime.h>
#include <hip/hip_bf16.h>

#define NB 4096
#define DD 768
#define NKT 12            // K-tiles of BK=64 (fp8): 768/64
#define NBLK 256          // grid: 256 blocks = 1 per CU (128KB LDS) -> all co-resident

typedef float f32x4 __attribute__((ext_vector_type(4)));
typedef long i64x2 __attribute__((ext_vector_type(2)));
typedef unsigned int uint;

#define WAITVM(N) asm volatile("s_waitcnt vmcnt(" #N ")" ::: "memory")

// ---------------- init: zero stats + barrier/flag state (d_ws is poisoned 0xAA) ----------------
// scal[0..2]=stats, scal[3]=np accumulator (int). bars[0..383]: tree group counters (g*16);
// bars[384]: root; bars[448]: release epoch; bars[464]: final ticket;
// bars[512 + p*16] p=0..31: panel-ready flags (8 producers each).
__global__ void init_kernel(float* scal, uint* bars)
{
    int t = threadIdx.x;
    if (t < 16) scal[t] = 0.0f;
    bars[t] = 0u;
    bars[512 + t] = 0u;
}

// ---------------- tree grid barrier (phase-coherent; used once, phase=1) ----------------
__device__ __forceinline__ void grid_bar(uint* bars, uint phase, int rawb, int t)
{
    __syncthreads();
    if (t == 0) {
        int g = rawb & 15;
        uint prev = __hip_atomic_fetch_add(&bars[g * 16], 1u, __ATOMIC_ACQ_REL, __HIP_MEMORY_SCOPE_AGENT);
        if (prev == phase * 16u - 1u) {
            uint r = __hip_atomic_fetch_add(&bars[384], 1u, __ATOMIC_ACQ_REL, __HIP_MEMORY_SCOPE_AGENT);
            if (r == phase * 16u - 1u)
                __hip_atomic_store(&bars[448], phase, __ATOMIC_RELEASE, __HIP_MEMORY_SCOPE_AGENT);
        }
        while (__hip_atomic_load(&bars[448], __ATOMIC_RELAXED, __HIP_MEMORY_SCOPE_AGENT) < phase)
            __builtin_amdgcn_s_sleep(8);
        (void)__hip_atomic_load(&bars[448], __ATOMIC_ACQUIRE, __HIP_MEMORY_SCOPE_AGENT);
    }
    __syncthreads();
}

// ---------------- staging: one K-tile unit = A[256][64B] + B[256][64B] fp8 (32 KB), ring-4 ----------------
// Rows are 64 B (4 chunks of 16 B): logical chunk c of row r at phys chunk c ^ ((r>>1)&3);
// linear LDS dest, pre-swizzled global source chunk (rule #21). Measured 0 bank conflicts.
__device__ __forceinline__ void stage_range(
    unsigned char* ldsAll,
    const unsigned char* __restrict__ vhat8, const unsigned char* __restrict__ that8,
    int rowBase, int colBase, int T, int i0, int i1, int wid, int lane)
{
    int u = T & 3;
    const unsigned char* src = (wid >= 4) ? that8 : vhat8;
    int tb = (wid >= 4) ? colBase : rowBase;
    int w4 = wid & 3;
    int logc = (lane & 3) ^ ((lane >> 3) & 3);
    int rowIn = w4 * 64 + (lane >> 2);
    unsigned char* dbase = ldsAll + u * 32768 + ((wid >= 4) ? 16384 : 0) + w4 * 4096;
    #pragma unroll
    for (int i = i0; i <= i1; ++i) {
        const unsigned char* g = src + (size_t)(tb + rowIn + i * 16) * DD + T * 64 + logc * 16;
        __builtin_amdgcn_global_load_lds(
            (const __attribute__((address_space(1))) void*)g,
            (__attribute__((address_space(3))) void*)(dbase + i * 1024),
            16, 0, 0);
    }
}

// ---------------- fully fused: normalize->fp8 | flags+poll | prologue||cnt | GEMM+stats | tree-bar | exp | ticket | loss ----------------
__global__ __launch_bounds__(512, 2) void fused_kernel(
    const float* __restrict__ vf, const float* __restrict__ tf, const int* __restrict__ ids,
    unsigned char* __restrict__ vhat8, unsigned char* __restrict__ that8,
    float* scal, float* rs, float* cs, float* cntf, uint* bars,
    float* __restrict__ out)
{
    __shared__ unsigned char ldsAll[4 * 32768];   // 128 KB ring; unit 3 doubles as ids stage in phase 0
    __shared__ int idr[256], idc[256];
    __shared__ float red[24];
    __shared__ float rs_l[256], cs_l[256];
    __shared__ int bp[16];
    __shared__ float ra[8], rn[8];
    __shared__ float invT_sh, mf_sh;
    __shared__ uint tick_sh;

    int* np_acc = (int*)(scal + 3);   // zeroed by init; accumulated via device-scope atomics
    int rawb = blockIdx.x;
    int t = threadIdx.x, wid = t >> 6, lane = t & 63;

    // ===== phase 0a: normalize 32 rows/block -> fp8 e4m3, identity k-layout (plain f32x4 loads) =====
    {
        f32x4 xr[4][3];
        uint* dsts[4];
        #pragma unroll
        for (int it = 0; it < 4; ++it) {
            int row = rawb * 32 + wid * 4 + it;
            const float* src;
            if (row < NB) { src = vf + (size_t)row * DD; dsts[it] = (uint*)(vhat8 + (size_t)row * DD); }
            else          { src = tf + (size_t)(row - NB) * DD; dsts[it] = (uint*)(that8 + (size_t)(row - NB) * DD); }
            xr[it][0] = *(const f32x4*)(src + lane * 4);
            xr[it][1] = *(const f32x4*)(src + 256 + lane * 4);
            xr[it][2] = *(const f32x4*)(src + 512 + lane * 4);
        }
        int idreg[8];
        #pragma unroll
        for (int i = 0; i < 8; ++i) idreg[i] = ids[t + i * 512];

        #pragma unroll
        for (int it = 0; it < 4; ++it) {
            float s = 0.f;
            #pragma unroll
            for (int c = 0; c < 3; ++c)
                s += xr[it][c][0]*xr[it][c][0] + xr[it][c][1]*xr[it][c][1]
                   + xr[it][c][2]*xr[it][c][2] + xr[it][c][3]*xr[it][c][3];
            #pragma unroll
            for (int off = 1; off < 64; off <<= 1) s += __shfl_xor(s, off, 64);
            float scale = 1.0f / sqrtf(s);
            #pragma unroll
            for (int c = 0; c < 3; ++c) {
                int p = __builtin_amdgcn_cvt_pk_fp8_f32(xr[it][c][0] * scale, xr[it][c][1] * scale, 0, false);
                p = __builtin_amdgcn_cvt_pk_fp8_f32(xr[it][c][2] * scale, xr[it][c][3] * scale, p, true);
                dsts[it][c * 64 + lane] = (uint)p;
            }
        }
        // ids -> LDS unit 3 (ring units 0-2 stay free for the GEMM prologue)
        int* idsh = (int*)(ldsAll + 3 * 32768);
        #pragma unroll
        for (int i = 0; i < 8; ++i) idsh[t + i * 512] = idreg[i];
    }
    __syncthreads();
    // panel-ready release: this block's 32 rows belong to combined panel rawb/8 (0..31)
    if (t == 0)
        __hip_atomic_fetch_add(&bars[512 + (rawb >> 3) * 16], 1u, __ATOMIC_ACQ_REL, __HIP_MEMORY_SCOPE_AGENT);

    // ===== GEMM geometry =====
    int rg = rawb & 7, sq = rawb >> 3;
    int by = (rg >> 1) * 4 + (sq >> 3);
    int bx = (rg & 1) * 8 + (sq & 7);
    int rowBase = by * 256, colBase = bx * 256;
    int wr = wid >> 2, wc = wid & 3;
    int fr = lane & 15, g = lane >> 4;

    // ===== panel-ready poll: need vhat panel `by` and that panel `bx` (8 producers each) =====
    if (t == 0) {
        uint* fA = &bars[512 + by * 16];
        uint* fB = &bars[512 + (16 + bx) * 16];
        while (__hip_atomic_load(fA, __ATOMIC_RELAXED, __HIP_MEMORY_SCOPE_AGENT) < 8u)
            __builtin_amdgcn_s_sleep(4);
        while (__hip_atomic_load(fB, __ATOMIC_RELAXED, __HIP_MEMORY_SCOPE_AGENT) < 8u)
            __builtin_amdgcn_s_sleep(4);
        (void)__hip_atomic_load(fA, __ATOMIC_ACQUIRE, __HIP_MEMORY_SCOPE_AGENT);
        (void)__hip_atomic_load(fB, __ATOMIC_ACQUIRE, __HIP_MEMORY_SCOPE_AGENT);
    }
    __syncthreads();

    // ===== prologue staging issued NOW; cnt/np/zero overlap the in-flight loads =====
    stage_range(ldsAll, vhat8, that8, rowBase, colBase, 0, 0, 3, wid, lane);
    stage_range(ldsAll, vhat8, that8, rowBase, colBase, 1, 0, 3, wid, lane);
    stage_range(ldsAll, vhat8, that8, rowBase, colBase, 2, 0, 3, wid, lane);

    // cnt — 32 lanes per id, int4 LDS scan (unit 3; staging writes units 0-2 only)
    {
        int* idsh = (int*)(ldsAll + 3 * 32768);
        int sub = t >> 5, l32 = t & 31;
        int my = idsh[rawb * 16 + sub];
        const int4* idsh4 = (const int4*)idsh;
        int c = 0;
        #pragma unroll 8
        for (int j = l32; j < NB / 4; j += 32) {
            int4 v = idsh4[j];
            c += (v.x == my) + (v.y == my) + (v.z == my) + (v.w == my);
        }
        #pragma unroll
        for (int off = 16; off > 0; off >>= 1) c += __shfl_down(c, off, 32);
        if (l32 == 0) { cntf[rawb * 16 + sub] = (float)c; bp[sub] = c; }
    }
    if (t < 32) rs[rawb * 32 + t] = 0.0f;   // zero rs+cs (contiguous 8192 floats)
    __syncthreads();
    if (t == 0) {
        int s = 0;
        #pragma unroll
        for (int i = 0; i < 16; ++i) s += bp[i];
        atomicAdd(np_acc, s);               // device-scope atomic: race-free np accumulation
    }
    WAITVM(8);                 // tile 0 staged (tiles 1,2 in flight)
    __builtin_amdgcn_s_barrier();

    // ===== GEMM: 256x256 tile, 8 waves, fp8 BK=64, ring-4, 2-phase =====
    f32x4 acc[8][4];
    #pragma unroll
    for (int m = 0; m < 8; ++m)
        #pragma unroll
        for (int n = 0; n < 4; ++n) acc[m][n] = (f32x4){0.f, 0.f, 0.f, 0.f};

    int pcoff = (g ^ ((fr >> 1) & 3)) * 16;
    int aoffB = (wr * 128 + fr) * 64 + pcoff;
    int boffB = 16384 + (wc * 64 + fr) * 64 + pcoff;

    for (int T = 0; T < NKT; ++T) {
        const unsigned char* U = ldsAll + (T & 3) * 32768;
        // phase A: reads(a0,bb) || stage half1(T+3) -> BAR -> MFMA m0..3 (x2 k-halves)
        i64x2 a0[4], bb[4];
        #pragma unroll
        for (int m = 0; m < 4; ++m) a0[m] = *(const i64x2*)(U + aoffB + m * 1024);
        #pragma unroll
        for (int n = 0; n < 4; ++n) bb[n] = *(const i64x2*)(U + boffB + n * 1024);
        if (T + 3 < NKT)
            stage_range(ldsAll, vhat8, that8, rowBase, colBase, T + 3, 0, 1, wid, lane);
        __builtin_amdgcn_s_barrier();
        __builtin_amdgcn_s_setprio(1);
        #pragma unroll
        for (int m = 0; m < 4; ++m)
            #pragma unroll
            for (int n = 0; n < 4; ++n) {
                acc[m][n] = __builtin_amdgcn_mfma_f32_16x16x32_fp8_fp8(a0[m][0], bb[n][0], acc[m][n], 0, 0, 0);
                acc[m][n] = __builtin_amdgcn_mfma_f32_16x16x32_fp8_fp8(a0[m][1], bb[n][1], acc[m][n], 0, 0, 0);
            }
        __builtin_amdgcn_s_setprio(0);
        __builtin_amdgcn_s_barrier();
        // phase B: reads(a1) || stage half2(T+3) -> BAR -> MFMA m4..7
        i64x2 a1[4];
        #pragma unroll
        for (int m = 0; m < 4; ++m) a1[m] = *(const i64x2*)(U + aoffB + (m + 4) * 1024);
        if (T + 3 < NKT)
            stage_range(ldsAll, vhat8, that8, rowBase, colBase, T + 3, 2, 3, wid, lane);
        __builtin_amdgcn_s_barrier();
        __builtin_amdgcn_s_setprio(1);
        #pragma unroll
        for (int m = 0; m < 4; ++m)
            #pragma unroll
            for (int n = 0; n < 4; ++n) {
                acc[m + 4][n] = __builtin_amdgcn_mfma_f32_16x16x32_fp8_fp8(a1[m][0], bb[n][0], acc[m + 4][n], 0, 0, 0);
                acc[m + 4][n] = __builtin_amdgcn_mfma_f32_16x16x32_fp8_fp8(a1[m][1], bb[n][1], acc[m + 4][n], 0, 0, 0);
            }
        __builtin_amdgcn_s_setprio(0);
        // tile boundary: T+1 staged; keep T+2/T+3 in flight (never vmcnt 0 mid-loop)
        if (T < NKT - 3)       { WAITVM(8); }
        else if (T == NKT - 3) { WAITVM(4); }
        else if (T == NKT - 2) { WAITVM(0); }
        __builtin_amdgcn_s_barrier();
    }

    // ===== stats: {total, S_mf, trace};  C/D: col=fr, row=g*4+reg [m89-verified, dtype-independent] =====
    if (t < 256) idr[t] = ids[rowBase + t];
    else         idc[t - 256] = ids[colBase + (t - 256)];
    __syncthreads();
    {
        float tsum = 0.f, msum = 0.f, dsum = 0.f;
        #pragma unroll
        for (int m = 0; m < 8; ++m) {
            int rl = wr * 128 + m * 16 + g * 4;
            #pragma unroll
            for (int n = 0; n < 4; ++n) {
                int cl = wc * 64 + n * 16 + fr;
                int colId = idc[cl];
                int gj = colBase + cl;
                #pragma unroll
                for (int r = 0; r < 4; ++r) {
                    float val = acc[m][n][r];
                    tsum += val;
                    if (idr[rl + r] == colId) msum += val;
                    if (rowBase + rl + r == gj) dsum += val;
                }
            }
        }
        #pragma unroll
        for (int off = 32; off > 0; off >>= 1) {
            tsum += __shfl_down(tsum, off, 64);
            msum += __shfl_down(msum, off, 64);
            dsum += __shfl_down(dsum, off, 64);
        }
        if (lane == 0) { red[wid] = tsum; red[8 + wid] = msum; red[16 + wid] = dsum; }
        __syncthreads();
        if (t == 0) {
            float s0 = 0.f, s1 = 0.f, s2 = 0.f;
            #pragma unroll
            for (int w = 0; w < 8; ++w) { s0 += red[w]; s1 += red[8 + w]; s2 += red[16 + w]; }
            atomicAdd(&scal[0], s0);
            atomicAdd(&scal[1], s1);
            atomicAdd(&scal[2], s2);
        }
    }
    if (t < 256) { rs_l[t] = 0.0f; cs_l[t] = 0.0f; }

    // ===== tree grid barrier (phase 1): stats + np complete =====
    grid_bar(bars, 1u, rawb, t);

    // ===== invT (t0 only; np via synchronized atomic) =====
    if (t == 0) {
        int npi = __hip_atomic_load(np_acc, __ATOMIC_RELAXED, __HIP_MEMORY_SCOPE_AGENT);
        float total = __hip_atomic_load(&scal[0], __ATOMIC_RELAXED, __HIP_MEMORY_SCOPE_AGENT);
        float mf    = __hip_atomic_load(&scal[1], __ATOMIC_RELAXED, __HIP_MEMORY_SCOPE_AGENT);
        float trace = __hip_atomic_load(&scal[2], __ATOMIC_RELAXED, __HIP_MEMORY_SCOPE_AGENT);
        float np = (float)npi;
        float pos_cnt = np - (float)NB;
        float neg_cnt = (float)NB * (float)NB - np;
        float pos_mean = (mf - trace) / fmaxf(1.0f, pos_cnt);
        float neg_mean = (total - mf) / fmaxf(1.0f, neg_cnt);
        float sep = pos_mean - neg_mean;
        float temp = 0.07f * (0.8f + 0.4f * expf(-2.0f * sep));
        temp = fminf(fmaxf(temp, 0.04f), 0.2f);
        invT_sh = 1.0f / temp;
        mf_sh = mf;
    }
    __syncthreads();
    float invT = invT_sh;

    // ===== exp((sim-1)/temp) row & col sums straight from registers =====
    #pragma unroll
    for (int m = 0; m < 8; ++m)
        #pragma unroll
        for (int n = 0; n < 4; ++n)
            #pragma unroll
            for (int r = 0; r < 4; ++r)
                acc[m][n][r] = __expf((acc[m][n][r] - 1.0f) * invT);
    #pragma unroll
    for (int m = 0; m < 8; ++m) {
        #pragma unroll
        for (int r = 0; r < 4; ++r) {
            float rp = 0.f;
            #pragma unroll
            for (int n = 0; n < 4; ++n) rp += acc[m][n][r];
            rp += __shfl_xor(rp, 1, 64);
            rp += __shfl_xor(rp, 2, 64);
            rp += __shfl_xor(rp, 4, 64);
            rp += __shfl_xor(rp, 8, 64);
            if (fr == 0) atomicAdd(&rs_l[wr * 128 + m * 16 + g * 4 + r], rp);
        }
    }
    #pragma unroll
    for (int n = 0; n < 4; ++n) {
        float cp = 0.f;
        #pragma unroll
        for (int m = 0; m < 8; ++m)
            #pragma unroll
            for (int r = 0; r < 4; ++r) cp += acc[m][n][r];
        cp += __shfl_xor(cp, 16, 64);
        cp += __shfl_xor(cp, 32, 64);
        if (g == 0) atomicAdd(&cs_l[wc * 64 + n * 16 + fr], cp);
    }
    __syncthreads();
    if (t < 256) {
        atomicAdd(&rs[rowBase + t], rs_l[t]);
        atomicAdd(&cs[colBase + t], cs_l[t]);
    }

    // ===== last-block ticket: the 256th arriver runs the final loss; everyone else exits =====
    __syncthreads();
    if (t == 0) {
        uint prev = __hip_atomic_fetch_add(&bars[464], 1u, __ATOMIC_ACQ_REL, __HIP_MEMORY_SCOPE_AGENT);
        tick_sh = prev;
    }
    __syncthreads();
    if (tick_sh != NBLK - 1) return;

    // ===== final loss (last-arriving block; its ACQ_REL RMW synchronized with all others) =====
    {
        float a = 0.f, npl = 0.f;
        for (int i = t; i < NB; i += 512) {
            float cf = cntf[i];
            a += cf * (logf(rs[i]) + logf(cs[i]));
            npl += cf;
        }
        #pragma unroll
        for (int off = 32; off > 0; off >>= 1) {
            a += __shfl_down(a, off, 64);
            npl += __shfl_down(npl, off, 64);
        }
        if (lane == 0) { ra[wid] = a; rn[wid] = npl; }
        __syncthreads();
        if (t == 0) {
            float A = 0.f, np = 0.f;
            #pragma unroll
            for (int w = 0; w < 8; ++w) { A += ra[w]; np += rn[w]; }
            // lse_row[i] = 1/temp + log(rs[i]); v2t+t2v = sum cnt*(lse_r+lse_c) - 2*mf/temp
            out[0] = (A + 2.0f * invT_sh * (np - mf_sh)) / (2.0f * np);
        }
    }
}

extern "C" void kernel_launch(void* const* d_in, const int* in_sizes, int n_in,
                              void* d_out, int out_size, void* d_ws, size_t ws_size,
                              hipStream_t stream)
{
    const float* vf  = (const float*)d_in[0];
    const float* tf  = (const float*)d_in[1];
    const int*   ids = (const int*)d_in[2];

    float* ws_f = (float*)d_ws;
    float* scal = ws_f;                 // [0]=total [1]=S_mf [2]=trace [3]=np accumulator (int)
    float* rs   = ws_f + 16;            // 4096  (cs contiguous after rs)
    float* cs   = ws_f + 16 + 4096;     // 4096
    float* cntf = ws_f + 16 + 8192;     // 4096
    uint* bars  = (uint*)(ws_f + 16 + 12800);  // 1024 words: tree barrier + ticket + panel flags
    unsigned char* vhat8 = (unsigned char*)d_ws + 131072;   // 4096*768 fp8 = 3 MB
    unsigned char* that8 = vhat8 + (size_t)NB * DD;

    init_kernel<<<1, 512, 0, stream>>>(scal, bars);
    fused_kernel<<<NBLK, 512, 0, stream>>>(vf, tf, ids, vhat8, that8,
                                           scal, rs, cs, cntf, bars, (float*)d_out);
}